// Round 3
// baseline (735.879 us; speedup 1.0000x reference)
//
#include <hip/hip_runtime.h>
#include <cstdint>
#include <cstddef>

// ---------------------------------------------------------------------------
// GIN forward, restructured:
//  L0: gather64(x)->planes; gemmP(64->128,+stats); fin; gemmF(128->128)->h1 f32
//  L1: gather128(h1)->planes; gemmP(128->128,+stats); fin; gemmF(128->128)->h2 planes
//  L2: gemmP(128->64, no bias) z; gather64(z,+b1)->y f32; stats; fin; gemmF(64->64)->out
// (layer-2 aggregation commuted through W1: (h+agg(h))@W1+b1 = z+agg(z)+b1)
// ---------------------------------------------------------------------------

static constexpr float BN_EPS_F = 1e-5f;

typedef __attribute__((ext_vector_type(8))) short bf16x8;
typedef __attribute__((ext_vector_type(4))) float f32x4;

__device__ __forceinline__ short bf16_rne(float f) {
    uint32_t u = __builtin_bit_cast(uint32_t, f);
    u += 0x7fffu + ((u >> 16) & 1u);
    return (short)(u >> 16);
}
__device__ __forceinline__ float bf16_f(short s) {
    uint32_t u = ((uint32_t)(uint16_t)s) << 16;
    return __builtin_bit_cast(float, u);
}

// ------------------------- CSR build kernels -------------------------------

__global__ __launch_bounds__(256) void hist_kernel(const int* __restrict__ dst,
                                                   int* __restrict__ deg, int E) {
    int e = blockIdx.x * 256 + threadIdx.x;
    if (e < E) atomicAdd(&deg[dst[e]], 1);
}

__global__ __launch_bounds__(1024) void scan_part_kernel(const int* __restrict__ deg,
                                                         int* __restrict__ ex,
                                                         int* __restrict__ bsum, int n) {
    __shared__ int sm[1024];
    int t = threadIdx.x;
    int g = blockIdx.x * 1024 + t;
    int v = (g < n) ? deg[g] : 0;
    sm[t] = v;
    __syncthreads();
    #pragma unroll
    for (int off = 1; off < 1024; off <<= 1) {
        int x = (t >= off) ? sm[t - off] : 0;
        __syncthreads();
        sm[t] += x;
        __syncthreads();
    }
    int incl = sm[t];
    if (g < n) ex[g] = incl - v;
    if (t == 1023) bsum[blockIdx.x] = incl;
}

__global__ __launch_bounds__(128) void scan_tops_kernel(int* __restrict__ bsum, int nb) {
    __shared__ int sm[128];
    int t = threadIdx.x;
    int v = (t < nb) ? bsum[t] : 0;
    sm[t] = v;
    __syncthreads();
    #pragma unroll
    for (int off = 1; off < 128; off <<= 1) {
        int x = (t >= off) ? sm[t - off] : 0;
        __syncthreads();
        sm[t] += x;
        __syncthreads();
    }
    if (t < nb) bsum[t] = sm[t] - v;
}

__global__ __launch_bounds__(1024) void scan_add_kernel(int* __restrict__ starts,
                                                        const int* __restrict__ bsum,
                                                        int n, int E) {
    int g = blockIdx.x * 1024 + threadIdx.x;
    if (g < n) starts[g] += bsum[blockIdx.x];
    if (g == 0) starts[n] = E;
}

__global__ __launch_bounds__(256) void fill_kernel(const int* __restrict__ src,
                                                   const int* __restrict__ dst,
                                                   int* __restrict__ cursor,
                                                   int* __restrict__ srcs, int E) {
    int e = blockIdx.x * 256 + threadIdx.x;
    if (e < E) {
        int d = dst[e];
        int p = atomicAdd(&cursor[d], 1);
        srcs[p] = src[e];
    }
}

// ------------------------- gather: out = x + segment_sum(x[src]) (+bias) ---
// 4 nodes per 256-thread block (one per wave). PLANES: write split-bf16 hi/lo.

template <int D, bool PLANES, bool BIAS>
__global__ __launch_bounds__(256) void gather_kernel(const float* __restrict__ x,
                                                     const int* __restrict__ starts,
                                                     const int* __restrict__ srcs,
                                                     const float* __restrict__ bias,
                                                     float* __restrict__ outf,
                                                     short* __restrict__ outh,
                                                     short* __restrict__ outl, int n) {
    int node = blockIdx.x * 4 + (threadIdx.x >> 6);
    int lane = threadIdx.x & 63;
    if (node >= n) return;
    int s = starts[node];
    int e = starts[node + 1];
    float a0 = x[(size_t)node * D + lane];
    float a1 = (D == 128) ? x[(size_t)node * D + 64 + lane] : 0.f;
    for (int j = s; j < e; ++j) {
        int sn = srcs[j];
        const float* row = x + (size_t)sn * D;
        a0 += row[lane];
        if (D == 128) a1 += row[64 + lane];
    }
    if (BIAS) {
        a0 += bias[lane];
        if (D == 128) a1 += bias[64 + lane];
    }
    size_t o0 = (size_t)node * D + lane;
    if (PLANES) {
        short h0 = bf16_rne(a0);
        outh[o0] = h0;
        outl[o0] = bf16_rne(a0 - bf16_f(h0));
        if (D == 128) {
            short h1 = bf16_rne(a1);
            outh[o0 + 64] = h1;
            outl[o0 + 64] = bf16_rne(a1 - bf16_f(h1));
        }
    } else {
        outf[o0] = a0;
        if (D == 128) outf[o0 + 64] = a1;
    }
}

// ------------------------- weight split (all 6 in one launch) --------------

struct WsArgs {
    const float* w[6];
    short* hi[6];
    short* lo[6];
    int K[6], Nc[6], base[6];
    int total;
};

__global__ __launch_bounds__(256) void wsplit_all(WsArgs a) {
    int idx = blockIdx.x * 256 + threadIdx.x;
    if (idx >= a.total) return;
    int s = 0;
    #pragma unroll
    for (int i = 1; i < 6; ++i)
        if (idx >= a.base[i]) s = i;
    int local = idx - a.base[s];
    int K = a.K[s], Nc = a.Nc[s];
    int n = local / K, k = local - n * K;
    float f = a.w[s][(size_t)k * Nc + n];
    short h = bf16_rne(f);
    a.hi[s][local] = h;
    a.lo[s][local] = bf16_rne(f - bf16_f(h));
}

// ------------------------- GEMM-P: C = planes(A) @ W (+bias) (+stats) ------
// A pre-split bf16 hi/lo [N][DI]; W pre-split bf16 [DO][DI].
// Block: 4 waves x 32 rows = 128 rows; per wave NF=DO/16 col fragments.

template <int DI, int DO, bool STATS, bool BIAS>
__global__ __launch_bounds__(256) void gemm_p(const short* __restrict__ Ah,
                                              const short* __restrict__ Al,
                                              const short* __restrict__ Wh,
                                              const short* __restrict__ Wl,
                                              const float* __restrict__ bias,
                                              float* __restrict__ C,
                                              float* __restrict__ sums, int nrows) {
    constexpr int NF = DO / 16;
    constexpr int KI = DI / 32;
    __shared__ float ssum[DO], sqsum[DO];

    const int t = threadIdx.x;
    if (STATS) {
        if (t < DO) { ssum[t] = 0.f; sqsum[t] = 0.f; }
        __syncthreads();
    }
    const int wave = t >> 6;
    const int lane = t & 63;
    const int lr = lane & 15;
    const int kb = lane >> 4;

    const int row_base = blockIdx.x * 128 + wave * 32;
    const int r0 = row_base + lr;
    const int r1 = r0 + 16;
    const short* a0h = Ah + (size_t)(r0 < nrows ? r0 : 0) * DI + kb * 8;
    const short* a1h = Ah + (size_t)(r1 < nrows ? r1 : 0) * DI + kb * 8;
    const short* a0l = Al + (a0h - Ah);
    const short* a1l = Al + (a1h - Ah);

    f32x4 acc[2][NF];
    #pragma unroll
    for (int m = 0; m < 2; ++m)
        #pragma unroll
        for (int nf = 0; nf < NF; ++nf) acc[m][nf] = f32x4{0.f, 0.f, 0.f, 0.f};

    #pragma unroll
    for (int ki = 0; ki < KI; ++ki) {
        const int k0 = ki * 32;
        bf16x8 ah0 = *reinterpret_cast<const bf16x8*>(a0h + k0);
        bf16x8 al0 = *reinterpret_cast<const bf16x8*>(a0l + k0);
        bf16x8 ah1 = *reinterpret_cast<const bf16x8*>(a1h + k0);
        bf16x8 al1 = *reinterpret_cast<const bf16x8*>(a1l + k0);
        #pragma unroll
        for (int nf = 0; nf < NF; ++nf) {
            const size_t woff = (size_t)(nf * 16 + lr) * DI + k0 + kb * 8;
            bf16x8 bh = *reinterpret_cast<const bf16x8*>(Wh + woff);
            bf16x8 bl = *reinterpret_cast<const bf16x8*>(Wl + woff);
            acc[0][nf] = __builtin_amdgcn_mfma_f32_16x16x32_bf16(ah0, bh, acc[0][nf], 0, 0, 0);
            acc[0][nf] = __builtin_amdgcn_mfma_f32_16x16x32_bf16(al0, bh, acc[0][nf], 0, 0, 0);
            acc[0][nf] = __builtin_amdgcn_mfma_f32_16x16x32_bf16(ah0, bl, acc[0][nf], 0, 0, 0);
            acc[1][nf] = __builtin_amdgcn_mfma_f32_16x16x32_bf16(ah1, bh, acc[1][nf], 0, 0, 0);
            acc[1][nf] = __builtin_amdgcn_mfma_f32_16x16x32_bf16(al1, bh, acc[1][nf], 0, 0, 0);
            acc[1][nf] = __builtin_amdgcn_mfma_f32_16x16x32_bf16(ah1, bl, acc[1][nf], 0, 0, 0);
        }
    }

    // epilogue: bias, store, fused stats
    #pragma unroll
    for (int nf = 0; nf < NF; ++nf) {
        const int col = nf * 16 + lr;
        const float b = BIAS ? bias[col] : 0.f;
        float s = 0.f, q = 0.f;
        #pragma unroll
        for (int mf = 0; mf < 2; ++mf) {
            const int rbase = row_base + mf * 16 + kb * 4;
            #pragma unroll
            for (int reg = 0; reg < 4; ++reg) {
                const int r = rbase + reg;
                const float val = acc[mf][nf][reg] + b;
                if (r < nrows) {
                    C[(size_t)r * DO + col] = val;
                    if (STATS) {
                        s += val;
                        q = fmaf(val, val, q);
                    }
                }
            }
        }
        if (STATS) {
            s += __shfl_xor(s, 16);
            s += __shfl_xor(s, 32);
            q += __shfl_xor(q, 16);
            q += __shfl_xor(q, 32);
            if (lane < 16) {
                atomicAdd(&ssum[col], s);
                atomicAdd(&sqsum[col], q);
            }
        }
    }
    if (STATS) {
        __syncthreads();
        if (t < DO) {
            atomicAdd(&sums[t], ssum[t]);
            atomicAdd(&sums[DO + t], sqsum[t]);
        }
    }
}

// ------------------------- GEMM-F: C = relu(BN(A)) @ W + bias --------------
// A fp32 [N][DI]; BN scale/shift per input col; split in-reg; OUTP: write planes.

template <int DI, int DO, bool OUTP>
__global__ __launch_bounds__(256) void gemm_f(const float* __restrict__ A,
                                              const short* __restrict__ Wh,
                                              const short* __restrict__ Wl,
                                              const float* __restrict__ bias,
                                              const float* __restrict__ scale,
                                              const float* __restrict__ shift,
                                              float* __restrict__ Cf,
                                              short* __restrict__ Ch,
                                              short* __restrict__ Cl, int nrows) {
    constexpr int NF = DO / 16;
    constexpr int KI = DI / 32;

    const int t = threadIdx.x;
    const int wave = t >> 6;
    const int lane = t & 63;
    const int lr = lane & 15;
    const int kb = lane >> 4;

    const int row_base = blockIdx.x * 128 + wave * 32;
    const int r0 = row_base + lr;
    const int r1 = r0 + 16;
    const float* a0p = A + (size_t)(r0 < nrows ? r0 : 0) * DI + kb * 8;
    const float* a1p = A + (size_t)(r1 < nrows ? r1 : 0) * DI + kb * 8;

    f32x4 acc[2][NF];
    #pragma unroll
    for (int m = 0; m < 2; ++m)
        #pragma unroll
        for (int nf = 0; nf < NF; ++nf) acc[m][nf] = f32x4{0.f, 0.f, 0.f, 0.f};

    #pragma unroll
    for (int ki = 0; ki < KI; ++ki) {
        const int k0 = ki * 32;
        f32x4 a0a = *reinterpret_cast<const f32x4*>(a0p + k0);
        f32x4 a0b = *reinterpret_cast<const f32x4*>(a0p + k0 + 4);
        f32x4 a1a = *reinterpret_cast<const f32x4*>(a1p + k0);
        f32x4 a1b = *reinterpret_cast<const f32x4*>(a1p + k0 + 4);
        {
            const int kk = k0 + kb * 8;
            f32x4 sca = *reinterpret_cast<const f32x4*>(scale + kk);
            f32x4 scb = *reinterpret_cast<const f32x4*>(scale + kk + 4);
            f32x4 sha = *reinterpret_cast<const f32x4*>(shift + kk);
            f32x4 shb = *reinterpret_cast<const f32x4*>(shift + kk + 4);
            #pragma unroll
            for (int j = 0; j < 4; ++j) {
                a0a[j] = fmaxf(fmaf(a0a[j], sca[j], sha[j]), 0.f);
                a0b[j] = fmaxf(fmaf(a0b[j], scb[j], shb[j]), 0.f);
                a1a[j] = fmaxf(fmaf(a1a[j], sca[j], sha[j]), 0.f);
                a1b[j] = fmaxf(fmaf(a1b[j], scb[j], shb[j]), 0.f);
            }
        }
        bf16x8 ah0, al0, ah1, al1;
        #pragma unroll
        for (int j = 0; j < 4; ++j) {
            short h;
            h = bf16_rne(a0a[j]); ah0[j] = h;     al0[j] = bf16_rne(a0a[j] - bf16_f(h));
            h = bf16_rne(a0b[j]); ah0[j + 4] = h; al0[j + 4] = bf16_rne(a0b[j] - bf16_f(h));
            h = bf16_rne(a1a[j]); ah1[j] = h;     al1[j] = bf16_rne(a1a[j] - bf16_f(h));
            h = bf16_rne(a1b[j]); ah1[j + 4] = h; al1[j + 4] = bf16_rne(a1b[j] - bf16_f(h));
        }
        #pragma unroll
        for (int nf = 0; nf < NF; ++nf) {
            const size_t woff = (size_t)(nf * 16 + lr) * DI + k0 + kb * 8;
            bf16x8 bh = *reinterpret_cast<const bf16x8*>(Wh + woff);
            bf16x8 bl = *reinterpret_cast<const bf16x8*>(Wl + woff);
            acc[0][nf] = __builtin_amdgcn_mfma_f32_16x16x32_bf16(ah0, bh, acc[0][nf], 0, 0, 0);
            acc[0][nf] = __builtin_amdgcn_mfma_f32_16x16x32_bf16(al0, bh, acc[0][nf], 0, 0, 0);
            acc[0][nf] = __builtin_amdgcn_mfma_f32_16x16x32_bf16(ah0, bl, acc[0][nf], 0, 0, 0);
            acc[1][nf] = __builtin_amdgcn_mfma_f32_16x16x32_bf16(ah1, bh, acc[1][nf], 0, 0, 0);
            acc[1][nf] = __builtin_amdgcn_mfma_f32_16x16x32_bf16(al1, bh, acc[1][nf], 0, 0, 0);
            acc[1][nf] = __builtin_amdgcn_mfma_f32_16x16x32_bf16(ah1, bl, acc[1][nf], 0, 0, 0);
        }
    }

    #pragma unroll
    for (int mf = 0; mf < 2; ++mf) {
        const int rbase = row_base + mf * 16 + kb * 4;
        #pragma unroll
        for (int nf = 0; nf < NF; ++nf) {
            const int col = nf * 16 + lr;
            const float b = bias[col];
            #pragma unroll
            for (int reg = 0; reg < 4; ++reg) {
                const int r = rbase + reg;
                if (r < nrows) {
                    const float val = acc[mf][nf][reg] + b;
                    const size_t idx = (size_t)r * DO + col;
                    if (OUTP) {
                        short h = bf16_rne(val);
                        Ch[idx] = h;
                        Cl[idx] = bf16_rne(val - bf16_f(h));
                    } else {
                        Cf[idx] = val;
                    }
                }
            }
        }
    }
}

// ------------------------- BN stats (used once, layer 2) -------------------

template <int DO>
__global__ __launch_bounds__(256) void stats_kernel(const float* __restrict__ H,
                                                    float* __restrict__ sums, int nrows) {
    constexpr int G = 256 / DO;
    int t = threadIdx.x;
    int col = t % DO;
    int grp = t / DO;
    float s = 0.f, s2 = 0.f;
    for (int r = blockIdx.x * G + grp; r < nrows; r += gridDim.x * G) {
        float v = H[(size_t)r * DO + col];
        s += v;
        s2 = fmaf(v, v, s2);
    }
    __shared__ float sm[256], sm2[256];
    sm[t] = s;
    sm2[t] = s2;
    __syncthreads();
    if (grp == 0) {
        #pragma unroll
        for (int g = 1; g < G; ++g) {
            s += sm[g * DO + col];
            s2 += sm2[g * DO + col];
        }
        atomicAdd(&sums[col], s);
        atomicAdd(&sums[DO + col], s2);
    }
}

template <int DO>
__global__ void bn_finalize_kernel(const float* __restrict__ sums,
                                   const float* __restrict__ g,
                                   const float* __restrict__ be,
                                   float* __restrict__ scsh, int nrows) {
    int c = threadIdx.x;
    if (c < DO) {
        float inv_n = 1.0f / (float)nrows;
        float mu = sums[c] * inv_n;
        float var = sums[DO + c] * inv_n - mu * mu;
        float inv = rsqrtf(var + BN_EPS_F);
        float sc = g[c] * inv;
        scsh[c] = sc;
        scsh[DO + c] = fmaf(-mu, sc, be[c]);
    }
}

// ------------------------- host orchestration ------------------------------

static inline size_t align_up(size_t v, size_t a) { return (v + a - 1) & ~(a - 1); }

extern "C" void kernel_launch(void* const* d_in, const int* in_sizes, int n_in,
                              void* d_out, int out_size, void* d_ws, size_t ws_size,
                              hipStream_t stream) {
    const float* x = (const float*)d_in[0];
    const int* ei = (const int*)d_in[1];
    const int N = in_sizes[0] / 64;
    const int E = in_sizes[1] / 2;
    const int* src = ei;
    const int* dst = ei + E;

    const float* w1[3]; const float* b1[3]; const float* gg[3];
    const float* be[3]; const float* w2[3]; const float* b2[3];
    for (int l = 0; l < 3; ++l) {
        w1[l] = (const float*)d_in[2 + 6 * l + 0];
        b1[l] = (const float*)d_in[2 + 6 * l + 1];
        gg[l] = (const float*)d_in[2 + 6 * l + 2];
        be[l] = (const float*)d_in[2 + 6 * l + 3];
        w2[l] = (const float*)d_in[2 + 6 * l + 4];
        b2[l] = (const float*)d_in[2 + 6 * l + 5];
    }

    char* ws = (char*)d_ws;
    size_t off = 0;
    auto alloc = [&](size_t bytes) {
        void* p = ws + off;
        off = align_up(off + bytes, 64);
        return p;
    };
    float* B0   = (float*)alloc((size_t)N * 128 * 4);   // t0 / t1 / y
    float* B1   = (float*)alloc((size_t)N * 128 * 4);   // h1 / z
    short* PH   = (short*)alloc((size_t)N * 128 * 2);   // pre planes / h2 planes
    short* PL   = (short*)alloc((size_t)N * 128 * 2);
    int* srcs   = (int*)alloc((size_t)E * 4);
    int* starts = (int*)alloc((size_t)(N + 1) * 4);
    int* cursor = (int*)alloc((size_t)N * 4);
    int* bsum   = (int*)alloc(256 * 4);
    float* sums = (float*)alloc(256 * 4);
    float* scsh = (float*)alloc(256 * 4);

    const int wdims[6][2] = {{64,128},{128,128},{128,128},{128,128},{128,64},{64,64}};
    const float* wsrc[6] = {w1[0], w2[0], w1[1], w2[1], w1[2], w2[2]};
    short* wh[6]; short* wl[6];
    WsArgs wa;
    int base = 0;
    for (int i = 0; i < 6; ++i) {
        int elems = wdims[i][0] * wdims[i][1];
        wh[i] = (short*)alloc((size_t)elems * 2);
        wl[i] = (short*)alloc((size_t)elems * 2);
        wa.w[i] = wsrc[i]; wa.hi[i] = wh[i]; wa.lo[i] = wl[i];
        wa.K[i] = wdims[i][0]; wa.Nc[i] = wdims[i][1]; wa.base[i] = base;
        base += elems;
    }
    wa.total = base;
    (void)ws_size; (void)n_in; (void)out_size;

    wsplit_all<<<(wa.total + 255) / 256, 256, 0, stream>>>(wa);

    // ---- CSR build ----
    hipMemsetAsync(cursor, 0, (size_t)N * 4, stream);
    hist_kernel<<<(E + 255) / 256, 256, 0, stream>>>(dst, cursor, E);
    int chunks = (N + 1023) / 1024;
    scan_part_kernel<<<chunks, 1024, 0, stream>>>(cursor, starts, bsum, N);
    scan_tops_kernel<<<1, 128, 0, stream>>>(bsum, chunks);
    scan_add_kernel<<<chunks, 1024, 0, stream>>>(starts, bsum, N, E);
    hipMemcpyAsync(cursor, starts, (size_t)N * 4, hipMemcpyDeviceToDevice, stream);
    fill_kernel<<<(E + 255) / 256, 256, 0, stream>>>(src, dst, cursor, srcs, E);

    const int nb = (N + 127) / 128;
    const int ng = (N + 3) / 4;

    // ---- layer 0 ----
    gather_kernel<64, true, false><<<ng, 256, 0, stream>>>(x, starts, srcs, nullptr,
                                                           nullptr, PH, PL, N);
    hipMemsetAsync(sums, 0, 2 * 128 * 4, stream);
    gemm_p<64, 128, true, true><<<nb, 256, 0, stream>>>(PH, PL, wh[0], wl[0], b1[0],
                                                        B0, sums, N);
    bn_finalize_kernel<128><<<1, 128, 0, stream>>>(sums, gg[0], be[0], scsh, N);
    gemm_f<128, 128, false><<<nb, 256, 0, stream>>>(B0, wh[1], wl[1], b2[0],
                                                    scsh, scsh + 128, B1, nullptr, nullptr, N);

    // ---- layer 1 ----
    gather_kernel<128, true, false><<<ng, 256, 0, stream>>>(B1, starts, srcs, nullptr,
                                                            nullptr, PH, PL, N);
    hipMemsetAsync(sums, 0, 2 * 128 * 4, stream);
    gemm_p<128, 128, true, true><<<nb, 256, 0, stream>>>(PH, PL, wh[2], wl[2], b1[1],
                                                         B0, sums, N);
    bn_finalize_kernel<128><<<1, 128, 0, stream>>>(sums, gg[1], be[1], scsh, N);
    gemm_f<128, 128, true><<<nb, 256, 0, stream>>>(B0, wh[3], wl[3], b2[1],
                                                   scsh, scsh + 128, nullptr, PH, PL, N);

    // ---- layer 2 (aggregation commuted through W1) ----
    gemm_p<128, 64, false, false><<<nb, 256, 0, stream>>>(PH, PL, wh[4], wl[4], nullptr,
                                                          B1, nullptr, N);
    gather_kernel<64, false, true><<<ng, 256, 0, stream>>>(B1, starts, srcs, b1[2],
                                                           B0, nullptr, nullptr, N);
    hipMemsetAsync(sums, 0, 2 * 64 * 4, stream);
    stats_kernel<64><<<512, 256, 0, stream>>>(B0, sums, N);
    bn_finalize_kernel<64><<<1, 64, 0, stream>>>(sums, gg[2], be[2], scsh, N);
    gemm_f<64, 64, false><<<nb, 256, 0, stream>>>(B0, wh[5], wl[5], b2[2],
                                                  scsh, scsh + 64, (float*)d_out, nullptr, nullptr, N);
}

// Round 4
// 594.474 us; speedup vs baseline: 1.2379x; 1.2379x over previous
//
#include <hip/hip_runtime.h>
#include <cstdint>
#include <cstddef>

// ---------------------------------------------------------------------------
// GIN forward, restructured:
//  L0: gather64(x)->planes; gemmP(64->128,+stats); fin; gemmF(128->128)->h1 f32
//  L1: gather128(h1)->planes; gemmP(128->128,+stats); fin; gemmF(128->128)->h2 planes
//  L2: gemmP(128->64, no bias) z; gather64(z,+b1)->y f32; stats; fin; gemmF(64->64)->out
// (layer-2 aggregation commuted through W1: (h+agg(h))@W1+b1 = z+agg(z)+b1)
// Gather: 1 wave per (node, 64-col half), 4-edge unrolled for MLP.
// ---------------------------------------------------------------------------

static constexpr float BN_EPS_F = 1e-5f;

typedef __attribute__((ext_vector_type(8))) short bf16x8;
typedef __attribute__((ext_vector_type(4))) float f32x4;

__device__ __forceinline__ short bf16_rne(float f) {
    uint32_t u = __builtin_bit_cast(uint32_t, f);
    u += 0x7fffu + ((u >> 16) & 1u);
    return (short)(u >> 16);
}
__device__ __forceinline__ float bf16_f(short s) {
    uint32_t u = ((uint32_t)(uint16_t)s) << 16;
    return __builtin_bit_cast(float, u);
}

// ------------------------- CSR build kernels -------------------------------

__global__ __launch_bounds__(256) void hist_kernel(const int* __restrict__ dst,
                                                   int* __restrict__ deg, int E) {
    int e = blockIdx.x * 256 + threadIdx.x;
    if (e < E) atomicAdd(&deg[dst[e]], 1);
}

__global__ __launch_bounds__(1024) void scan_part_kernel(const int* __restrict__ deg,
                                                         int* __restrict__ ex,
                                                         int* __restrict__ bsum, int n) {
    __shared__ int sm[1024];
    int t = threadIdx.x;
    int g = blockIdx.x * 1024 + t;
    int v = (g < n) ? deg[g] : 0;
    sm[t] = v;
    __syncthreads();
    #pragma unroll
    for (int off = 1; off < 1024; off <<= 1) {
        int x = (t >= off) ? sm[t - off] : 0;
        __syncthreads();
        sm[t] += x;
        __syncthreads();
    }
    int incl = sm[t];
    if (g < n) ex[g] = incl - v;
    if (t == 1023) bsum[blockIdx.x] = incl;
}

__global__ __launch_bounds__(128) void scan_tops_kernel(int* __restrict__ bsum, int nb) {
    __shared__ int sm[128];
    int t = threadIdx.x;
    int v = (t < nb) ? bsum[t] : 0;
    sm[t] = v;
    __syncthreads();
    #pragma unroll
    for (int off = 1; off < 128; off <<= 1) {
        int x = (t >= off) ? sm[t - off] : 0;
        __syncthreads();
        sm[t] += x;
        __syncthreads();
    }
    if (t < nb) bsum[t] = sm[t] - v;
}

__global__ __launch_bounds__(1024) void scan_add_kernel(int* __restrict__ starts,
                                                        const int* __restrict__ bsum,
                                                        int n, int E) {
    int g = blockIdx.x * 1024 + threadIdx.x;
    if (g < n) starts[g] += bsum[blockIdx.x];
    if (g == 0) starts[n] = E;
}

__global__ __launch_bounds__(256) void fill_kernel(const int* __restrict__ src,
                                                   const int* __restrict__ dst,
                                                   int* __restrict__ cursor,
                                                   int* __restrict__ srcs, int E) {
    int e = blockIdx.x * 256 + threadIdx.x;
    if (e < E) {
        int d = dst[e];
        int p = atomicAdd(&cursor[d], 1);
        srcs[p] = src[e];
    }
}

// ------------------------- gather: out = x + segment_sum(x[src]) (+bias) ---
// 1 wave per (node, half). D=128 -> 2 blocks/node; D=64 -> 1. 4-edge unroll.

template <int D, bool PLANES, bool BIAS>
__global__ __launch_bounds__(64) void gather_kernel(const float* __restrict__ x,
                                                    const int* __restrict__ starts,
                                                    const int* __restrict__ srcs,
                                                    const float* __restrict__ bias,
                                                    float* __restrict__ outf,
                                                    short* __restrict__ outh,
                                                    short* __restrict__ outl, int n) {
    constexpr int H = D / 64;
    const int bid = blockIdx.x;
    const int node = (H == 2) ? (bid >> 1) : bid;
    const int col = ((H == 2) ? (bid & 1) * 64 : 0) + threadIdx.x;
    const int s = starts[node];
    const int e = starts[node + 1];

    float a = x[(size_t)node * D + col];
    int j = s;
    for (; j + 4 <= e; j += 4) {
        int s0 = srcs[j];
        int s1 = srcs[j + 1];
        int s2 = srcs[j + 2];
        int s3 = srcs[j + 3];
        float v0 = x[(size_t)s0 * D + col];
        float v1 = x[(size_t)s1 * D + col];
        float v2 = x[(size_t)s2 * D + col];
        float v3 = x[(size_t)s3 * D + col];
        a += (v0 + v1) + (v2 + v3);
    }
    for (; j < e; ++j) a += x[(size_t)srcs[j] * D + col];

    if (BIAS) a += bias[col];
    const size_t o = (size_t)node * D + col;
    if (PLANES) {
        short h = bf16_rne(a);
        outh[o] = h;
        outl[o] = bf16_rne(a - bf16_f(h));
    } else {
        outf[o] = a;
    }
}

// ------------------------- weight split (all 6 in one launch) --------------

struct WsArgs {
    const float* w[6];
    short* hi[6];
    short* lo[6];
    int K[6], Nc[6], base[6];
    int total;
};

__global__ __launch_bounds__(256) void wsplit_all(WsArgs a) {
    int idx = blockIdx.x * 256 + threadIdx.x;
    if (idx >= a.total) return;
    int s = 0;
    #pragma unroll
    for (int i = 1; i < 6; ++i)
        if (idx >= a.base[i]) s = i;
    int local = idx - a.base[s];
    int K = a.K[s], Nc = a.Nc[s];
    int n = local / K, k = local - n * K;
    float f = a.w[s][(size_t)k * Nc + n];
    short h = bf16_rne(f);
    a.hi[s][local] = h;
    a.lo[s][local] = bf16_rne(f - bf16_f(h));
}

// ------------------------- GEMM-P: C = planes(A) @ W (+bias) (+stats) ------
// A pre-split bf16 hi/lo [N][DI]; W pre-split bf16 [DO][DI].
// Block: 4 waves x 32 rows = 128 rows; per wave NF=DO/16 col fragments.

template <int DI, int DO, bool STATS, bool BIAS>
__global__ __launch_bounds__(256) void gemm_p(const short* __restrict__ Ah,
                                              const short* __restrict__ Al,
                                              const short* __restrict__ Wh,
                                              const short* __restrict__ Wl,
                                              const float* __restrict__ bias,
                                              float* __restrict__ C,
                                              float* __restrict__ sums, int nrows) {
    constexpr int NF = DO / 16;
    constexpr int KI = DI / 32;
    __shared__ float ssum[DO], sqsum[DO];

    const int t = threadIdx.x;
    if (STATS) {
        if (t < DO) { ssum[t] = 0.f; sqsum[t] = 0.f; }
        __syncthreads();
    }
    const int wave = t >> 6;
    const int lane = t & 63;
    const int lr = lane & 15;
    const int kb = lane >> 4;

    const int row_base = blockIdx.x * 128 + wave * 32;
    const int r0 = row_base + lr;
    const int r1 = r0 + 16;
    const short* a0h = Ah + (size_t)(r0 < nrows ? r0 : 0) * DI + kb * 8;
    const short* a1h = Ah + (size_t)(r1 < nrows ? r1 : 0) * DI + kb * 8;
    const short* a0l = Al + (a0h - Ah);
    const short* a1l = Al + (a1h - Ah);

    f32x4 acc[2][NF];
    #pragma unroll
    for (int m = 0; m < 2; ++m)
        #pragma unroll
        for (int nf = 0; nf < NF; ++nf) acc[m][nf] = f32x4{0.f, 0.f, 0.f, 0.f};

    #pragma unroll
    for (int ki = 0; ki < KI; ++ki) {
        const int k0 = ki * 32;
        bf16x8 ah0 = *reinterpret_cast<const bf16x8*>(a0h + k0);
        bf16x8 al0 = *reinterpret_cast<const bf16x8*>(a0l + k0);
        bf16x8 ah1 = *reinterpret_cast<const bf16x8*>(a1h + k0);
        bf16x8 al1 = *reinterpret_cast<const bf16x8*>(a1l + k0);
        #pragma unroll
        for (int nf = 0; nf < NF; ++nf) {
            const size_t woff = (size_t)(nf * 16 + lr) * DI + k0 + kb * 8;
            bf16x8 bh = *reinterpret_cast<const bf16x8*>(Wh + woff);
            bf16x8 bl = *reinterpret_cast<const bf16x8*>(Wl + woff);
            acc[0][nf] = __builtin_amdgcn_mfma_f32_16x16x32_bf16(ah0, bh, acc[0][nf], 0, 0, 0);
            acc[0][nf] = __builtin_amdgcn_mfma_f32_16x16x32_bf16(al0, bh, acc[0][nf], 0, 0, 0);
            acc[0][nf] = __builtin_amdgcn_mfma_f32_16x16x32_bf16(ah0, bl, acc[0][nf], 0, 0, 0);
            acc[1][nf] = __builtin_amdgcn_mfma_f32_16x16x32_bf16(ah1, bh, acc[1][nf], 0, 0, 0);
            acc[1][nf] = __builtin_amdgcn_mfma_f32_16x16x32_bf16(al1, bh, acc[1][nf], 0, 0, 0);
            acc[1][nf] = __builtin_amdgcn_mfma_f32_16x16x32_bf16(ah1, bl, acc[1][nf], 0, 0, 0);
        }
    }

    // epilogue: bias, store, fused stats
    #pragma unroll
    for (int nf = 0; nf < NF; ++nf) {
        const int col = nf * 16 + lr;
        const float b = BIAS ? bias[col] : 0.f;
        float s = 0.f, q = 0.f;
        #pragma unroll
        for (int mf = 0; mf < 2; ++mf) {
            const int rbase = row_base + mf * 16 + kb * 4;
            #pragma unroll
            for (int reg = 0; reg < 4; ++reg) {
                const int r = rbase + reg;
                const float val = acc[mf][nf][reg] + b;
                if (r < nrows) {
                    C[(size_t)r * DO + col] = val;
                    if (STATS) {
                        s += val;
                        q = fmaf(val, val, q);
                    }
                }
            }
        }
        if (STATS) {
            s += __shfl_xor(s, 16);
            s += __shfl_xor(s, 32);
            q += __shfl_xor(q, 16);
            q += __shfl_xor(q, 32);
            if (lane < 16) {
                atomicAdd(&ssum[col], s);
                atomicAdd(&sqsum[col], q);
            }
        }
    }
    if (STATS) {
        __syncthreads();
        if (t < DO) {
            atomicAdd(&sums[t], ssum[t]);
            atomicAdd(&sums[DO + t], sqsum[t]);
        }
    }
}

// ------------------------- GEMM-F: C = relu(BN(A)) @ W + bias --------------
// A fp32 [N][DI]; BN scale/shift per input col; split in-reg; OUTP: write planes.

template <int DI, int DO, bool OUTP>
__global__ __launch_bounds__(256) void gemm_f(const float* __restrict__ A,
                                              const short* __restrict__ Wh,
                                              const short* __restrict__ Wl,
                                              const float* __restrict__ bias,
                                              const float* __restrict__ scale,
                                              const float* __restrict__ shift,
                                              float* __restrict__ Cf,
                                              short* __restrict__ Ch,
                                              short* __restrict__ Cl, int nrows) {
    constexpr int NF = DO / 16;
    constexpr int KI = DI / 32;

    const int t = threadIdx.x;
    const int wave = t >> 6;
    const int lane = t & 63;
    const int lr = lane & 15;
    const int kb = lane >> 4;

    const int row_base = blockIdx.x * 128 + wave * 32;
    const int r0 = row_base + lr;
    const int r1 = r0 + 16;
    const float* a0p = A + (size_t)(r0 < nrows ? r0 : 0) * DI + kb * 8;
    const float* a1p = A + (size_t)(r1 < nrows ? r1 : 0) * DI + kb * 8;

    f32x4 acc[2][NF];
    #pragma unroll
    for (int m = 0; m < 2; ++m)
        #pragma unroll
        for (int nf = 0; nf < NF; ++nf) acc[m][nf] = f32x4{0.f, 0.f, 0.f, 0.f};

    #pragma unroll
    for (int ki = 0; ki < KI; ++ki) {
        const int k0 = ki * 32;
        f32x4 a0a = *reinterpret_cast<const f32x4*>(a0p + k0);
        f32x4 a0b = *reinterpret_cast<const f32x4*>(a0p + k0 + 4);
        f32x4 a1a = *reinterpret_cast<const f32x4*>(a1p + k0);
        f32x4 a1b = *reinterpret_cast<const f32x4*>(a1p + k0 + 4);
        {
            const int kk = k0 + kb * 8;
            f32x4 sca = *reinterpret_cast<const f32x4*>(scale + kk);
            f32x4 scb = *reinterpret_cast<const f32x4*>(scale + kk + 4);
            f32x4 sha = *reinterpret_cast<const f32x4*>(shift + kk);
            f32x4 shb = *reinterpret_cast<const f32x4*>(shift + kk + 4);
            #pragma unroll
            for (int j = 0; j < 4; ++j) {
                a0a[j] = fmaxf(fmaf(a0a[j], sca[j], sha[j]), 0.f);
                a0b[j] = fmaxf(fmaf(a0b[j], scb[j], shb[j]), 0.f);
                a1a[j] = fmaxf(fmaf(a1a[j], sca[j], sha[j]), 0.f);
                a1b[j] = fmaxf(fmaf(a1b[j], scb[j], shb[j]), 0.f);
            }
        }
        bf16x8 ah0, al0, ah1, al1;
        #pragma unroll
        for (int j = 0; j < 4; ++j) {
            short h;
            h = bf16_rne(a0a[j]); ah0[j] = h;     al0[j] = bf16_rne(a0a[j] - bf16_f(h));
            h = bf16_rne(a0b[j]); ah0[j + 4] = h; al0[j + 4] = bf16_rne(a0b[j] - bf16_f(h));
            h = bf16_rne(a1a[j]); ah1[j] = h;     al1[j] = bf16_rne(a1a[j] - bf16_f(h));
            h = bf16_rne(a1b[j]); ah1[j + 4] = h; al1[j + 4] = bf16_rne(a1b[j] - bf16_f(h));
        }
        #pragma unroll
        for (int nf = 0; nf < NF; ++nf) {
            const size_t woff = (size_t)(nf * 16 + lr) * DI + k0 + kb * 8;
            bf16x8 bh = *reinterpret_cast<const bf16x8*>(Wh + woff);
            bf16x8 bl = *reinterpret_cast<const bf16x8*>(Wl + woff);
            acc[0][nf] = __builtin_amdgcn_mfma_f32_16x16x32_bf16(ah0, bh, acc[0][nf], 0, 0, 0);
            acc[0][nf] = __builtin_amdgcn_mfma_f32_16x16x32_bf16(al0, bh, acc[0][nf], 0, 0, 0);
            acc[0][nf] = __builtin_amdgcn_mfma_f32_16x16x32_bf16(ah0, bl, acc[0][nf], 0, 0, 0);
            acc[1][nf] = __builtin_amdgcn_mfma_f32_16x16x32_bf16(ah1, bh, acc[1][nf], 0, 0, 0);
            acc[1][nf] = __builtin_amdgcn_mfma_f32_16x16x32_bf16(al1, bh, acc[1][nf], 0, 0, 0);
            acc[1][nf] = __builtin_amdgcn_mfma_f32_16x16x32_bf16(ah1, bl, acc[1][nf], 0, 0, 0);
        }
    }

    #pragma unroll
    for (int mf = 0; mf < 2; ++mf) {
        const int rbase = row_base + mf * 16 + kb * 4;
        #pragma unroll
        for (int nf = 0; nf < NF; ++nf) {
            const int col = nf * 16 + lr;
            const float b = bias[col];
            #pragma unroll
            for (int reg = 0; reg < 4; ++reg) {
                const int r = rbase + reg;
                if (r < nrows) {
                    const float val = acc[mf][nf][reg] + b;
                    const size_t idx = (size_t)r * DO + col;
                    if (OUTP) {
                        short h = bf16_rne(val);
                        Ch[idx] = h;
                        Cl[idx] = bf16_rne(val - bf16_f(h));
                    } else {
                        Cf[idx] = val;
                    }
                }
            }
        }
    }
}

// ------------------------- BN stats (used once, layer 2) -------------------

template <int DO>
__global__ __launch_bounds__(256) void stats_kernel(const float* __restrict__ H,
                                                    float* __restrict__ sums, int nrows) {
    constexpr int G = 256 / DO;
    int t = threadIdx.x;
    int col = t % DO;
    int grp = t / DO;
    float s = 0.f, s2 = 0.f;
    for (int r = blockIdx.x * G + grp; r < nrows; r += gridDim.x * G) {
        float v = H[(size_t)r * DO + col];
        s += v;
        s2 = fmaf(v, v, s2);
    }
    __shared__ float sm[256], sm2[256];
    sm[t] = s;
    sm2[t] = s2;
    __syncthreads();
    if (grp == 0) {
        #pragma unroll
        for (int g = 1; g < G; ++g) {
            s += sm[g * DO + col];
            s2 += sm2[g * DO + col];
        }
        atomicAdd(&sums[col], s);
        atomicAdd(&sums[DO + col], s2);
    }
}

template <int DO>
__global__ void bn_finalize_kernel(const float* __restrict__ sums,
                                   const float* __restrict__ g,
                                   const float* __restrict__ be,
                                   float* __restrict__ scsh, int nrows) {
    int c = threadIdx.x;
    if (c < DO) {
        float inv_n = 1.0f / (float)nrows;
        float mu = sums[c] * inv_n;
        float var = sums[DO + c] * inv_n - mu * mu;
        float inv = rsqrtf(var + BN_EPS_F);
        float sc = g[c] * inv;
        scsh[c] = sc;
        scsh[DO + c] = fmaf(-mu, sc, be[c]);
    }
}

// ------------------------- host orchestration ------------------------------

static inline size_t align_up(size_t v, size_t a) { return (v + a - 1) & ~(a - 1); }

extern "C" void kernel_launch(void* const* d_in, const int* in_sizes, int n_in,
                              void* d_out, int out_size, void* d_ws, size_t ws_size,
                              hipStream_t stream) {
    const float* x = (const float*)d_in[0];
    const int* ei = (const int*)d_in[1];
    const int N = in_sizes[0] / 64;
    const int E = in_sizes[1] / 2;
    const int* src = ei;
    const int* dst = ei + E;

    const float* w1[3]; const float* b1[3]; const float* gg[3];
    const float* be[3]; const float* w2[3]; const float* b2[3];
    for (int l = 0; l < 3; ++l) {
        w1[l] = (const float*)d_in[2 + 6 * l + 0];
        b1[l] = (const float*)d_in[2 + 6 * l + 1];
        gg[l] = (const float*)d_in[2 + 6 * l + 2];
        be[l] = (const float*)d_in[2 + 6 * l + 3];
        w2[l] = (const float*)d_in[2 + 6 * l + 4];
        b2[l] = (const float*)d_in[2 + 6 * l + 5];
    }

    char* ws = (char*)d_ws;
    size_t off = 0;
    auto alloc = [&](size_t bytes) {
        void* p = ws + off;
        off = align_up(off + bytes, 64);
        return p;
    };
    float* B0   = (float*)alloc((size_t)N * 128 * 4);   // t0 / t1 / y
    float* B1   = (float*)alloc((size_t)N * 128 * 4);   // h1 / z
    short* PH   = (short*)alloc((size_t)N * 128 * 2);   // pre planes / h2 planes
    short* PL   = (short*)alloc((size_t)N * 128 * 2);
    int* srcs   = (int*)alloc((size_t)E * 4);
    int* starts = (int*)alloc((size_t)(N + 1) * 4);
    int* cursor = (int*)alloc((size_t)N * 4);
    int* bsum   = (int*)alloc(256 * 4);
    float* sums = (float*)alloc(256 * 4);
    float* scsh = (float*)alloc(256 * 4);

    const int wdims[6][2] = {{64,128},{128,128},{128,128},{128,128},{128,64},{64,64}};
    const float* wsrc[6] = {w1[0], w2[0], w1[1], w2[1], w1[2], w2[2]};
    short* wh[6]; short* wl[6];
    WsArgs wa;
    int base = 0;
    for (int i = 0; i < 6; ++i) {
        int elems = wdims[i][0] * wdims[i][1];
        wh[i] = (short*)alloc((size_t)elems * 2);
        wl[i] = (short*)alloc((size_t)elems * 2);
        wa.w[i] = wsrc[i]; wa.hi[i] = wh[i]; wa.lo[i] = wl[i];
        wa.K[i] = wdims[i][0]; wa.Nc[i] = wdims[i][1]; wa.base[i] = base;
        base += elems;
    }
    wa.total = base;
    (void)ws_size; (void)n_in; (void)out_size;

    wsplit_all<<<(wa.total + 255) / 256, 256, 0, stream>>>(wa);

    // ---- CSR build ----
    hipMemsetAsync(cursor, 0, (size_t)N * 4, stream);
    hist_kernel<<<(E + 255) / 256, 256, 0, stream>>>(dst, cursor, E);
    int chunks = (N + 1023) / 1024;
    scan_part_kernel<<<chunks, 1024, 0, stream>>>(cursor, starts, bsum, N);
    scan_tops_kernel<<<1, 128, 0, stream>>>(bsum, chunks);
    scan_add_kernel<<<chunks, 1024, 0, stream>>>(starts, bsum, N, E);
    hipMemcpyAsync(cursor, starts, (size_t)N * 4, hipMemcpyDeviceToDevice, stream);
    fill_kernel<<<(E + 255) / 256, 256, 0, stream>>>(src, dst, cursor, srcs, E);

    const int nb = (N + 127) / 128;

    // ---- layer 0 ----
    gather_kernel<64, true, false><<<N, 64, 0, stream>>>(x, starts, srcs, nullptr,
                                                         nullptr, PH, PL, N);
    hipMemsetAsync(sums, 0, 2 * 128 * 4, stream);
    gemm_p<64, 128, true, true><<<nb, 256, 0, stream>>>(PH, PL, wh[0], wl[0], b1[0],
                                                        B0, sums, N);
    bn_finalize_kernel<128><<<1, 128, 0, stream>>>(sums, gg[0], be[0], scsh, N);
    gemm_f<128, 128, false><<<nb, 256, 0, stream>>>(B0, wh[1], wl[1], b2[0],
                                                    scsh, scsh + 128, B1, nullptr, nullptr, N);

    // ---- layer 1 ----
    gather_kernel<128, true, false><<<2 * N, 64, 0, stream>>>(B1, starts, srcs, nullptr,
                                                              nullptr, PH, PL, N);
    hipMemsetAsync(sums, 0, 2 * 128 * 4, stream);
    gemm_p<128, 128, true, true><<<nb, 256, 0, stream>>>(PH, PL, wh[2], wl[2], b1[1],
                                                         B0, sums, N);
    bn_finalize_kernel<128><<<1, 128, 0, stream>>>(sums, gg[1], be[1], scsh, N);
    gemm_f<128, 128, true><<<nb, 256, 0, stream>>>(B0, wh[3], wl[3], b2[1],
                                                   scsh, scsh + 128, nullptr, PH, PL, N);

    // ---- layer 2 (aggregation commuted through W1) ----
    gemm_p<128, 64, false, false><<<nb, 256, 0, stream>>>(PH, PL, wh[4], wl[4], nullptr,
                                                          B1, nullptr, N);
    gather_kernel<64, false, true><<<N, 64, 0, stream>>>(B1, starts, srcs, b1[2],
                                                         B0, nullptr, nullptr, N);
    hipMemsetAsync(sums, 0, 2 * 64 * 4, stream);
    stats_kernel<64><<<512, 256, 0, stream>>>(B0, sums, N);
    bn_finalize_kernel<64><<<1, 64, 0, stream>>>(sums, gg[2], be[2], scsh, N);
    gemm_f<64, 64, false><<<nb, 256, 0, stream>>>(B0, wh[5], wl[5], b2[2],
                                                  scsh, scsh + 64, (float*)d_out, nullptr, nullptr, N);
}

// Round 5
// 590.987 us; speedup vs baseline: 1.2452x; 1.0059x over previous
//
#include <hip/hip_runtime.h>
#include <cstdint>
#include <cstddef>

// ---------------------------------------------------------------------------
// GIN forward:
//  L0: gather64(x)->planes(+zero sums); gemmP(64->128,+stats); gemmF(128->128,fin inline)->h1
//  L1: gather128(h1)->planes(+zero sums); gemmP(128->128,+stats); gemmF(fin)->h2 planes
//  L2: gemmP(128->64) z; gather64(z,+b1,+zero sums)->y; stats; gemmF(64->64,fin)->out
// (layer-2 aggregation commuted through W1; BN finalize inlined into gemm_f)
// Gather: 1 wave per (node, 64-col half); 4 groups x 16 lanes, float4/lane,
// one load instruction = 4 edge rows; 2x unroll = 8 edges in flight.
// ---------------------------------------------------------------------------

static constexpr float BN_EPS_F = 1e-5f;

typedef __attribute__((ext_vector_type(8))) short bf16x8;
typedef __attribute__((ext_vector_type(4))) float f32x4;

__device__ __forceinline__ short bf16_rne(float f) {
    uint32_t u = __builtin_bit_cast(uint32_t, f);
    u += 0x7fffu + ((u >> 16) & 1u);
    return (short)(u >> 16);
}
__device__ __forceinline__ float bf16_f(short s) {
    uint32_t u = ((uint32_t)(uint16_t)s) << 16;
    return __builtin_bit_cast(float, u);
}

// ------------------------- CSR build kernels -------------------------------

__global__ __launch_bounds__(256) void hist_kernel(const int* __restrict__ dst,
                                                   int* __restrict__ deg, int E) {
    int e = blockIdx.x * 256 + threadIdx.x;
    if (e < E) atomicAdd(&deg[dst[e]], 1);
}

__global__ __launch_bounds__(1024) void scan_part_kernel(const int* __restrict__ deg,
                                                         int* __restrict__ ex,
                                                         int* __restrict__ bsum, int n) {
    __shared__ int sm[1024];
    int t = threadIdx.x;
    int g = blockIdx.x * 1024 + t;
    int v = (g < n) ? deg[g] : 0;
    sm[t] = v;
    __syncthreads();
    #pragma unroll
    for (int off = 1; off < 1024; off <<= 1) {
        int x = (t >= off) ? sm[t - off] : 0;
        __syncthreads();
        sm[t] += x;
        __syncthreads();
    }
    int incl = sm[t];
    if (g < n) ex[g] = incl - v;
    if (t == 1023) bsum[blockIdx.x] = incl;
}

__global__ __launch_bounds__(128) void scan_tops_kernel(int* __restrict__ bsum, int nb) {
    __shared__ int sm[128];
    int t = threadIdx.x;
    int v = (t < nb) ? bsum[t] : 0;
    sm[t] = v;
    __syncthreads();
    #pragma unroll
    for (int off = 1; off < 128; off <<= 1) {
        int x = (t >= off) ? sm[t - off] : 0;
        __syncthreads();
        sm[t] += x;
        __syncthreads();
    }
    if (t < nb) bsum[t] = sm[t] - v;
}

__global__ __launch_bounds__(1024) void scan_add_kernel(int* __restrict__ starts,
                                                        int* __restrict__ cursor,
                                                        const int* __restrict__ bsum,
                                                        int n, int E) {
    int g = blockIdx.x * 1024 + threadIdx.x;
    if (g < n) {
        int v = starts[g] + bsum[blockIdx.x];
        starts[g] = v;
        cursor[g] = v;
    }
    if (g == 0) starts[n] = E;
}

__global__ __launch_bounds__(256) void fill_kernel(const int* __restrict__ src,
                                                   const int* __restrict__ dst,
                                                   int* __restrict__ cursor,
                                                   int* __restrict__ srcs, int E) {
    int e = blockIdx.x * 256 + threadIdx.x;
    if (e < E) {
        int d = dst[e];
        int p = atomicAdd(&cursor[d], 1);
        srcs[p] = src[e];
    }
}

// ------------------------- gather: out = x + segment_sum(x[src]) (+bias) ---
// 1 wave per (node, 64-col half). 4 edge-groups x 16 lanes x float4.

template <int D, bool PLANES, bool BIAS, bool ZSUMS>
__global__ __launch_bounds__(64) void gather_kernel(const float* __restrict__ x,
                                                    const int* __restrict__ starts,
                                                    const int* __restrict__ srcs,
                                                    const float* __restrict__ bias,
                                                    float* __restrict__ outf,
                                                    short* __restrict__ outh,
                                                    short* __restrict__ outl,
                                                    float* __restrict__ sums,
                                                    int nsum, int n) {
    constexpr int H = D / 64;
    const int bid = blockIdx.x;
    const int lane = threadIdx.x;
    if (ZSUMS && bid == 0) {
        for (int i = lane; i < nsum; i += 64) sums[i] = 0.f;
    }
    const int node = (H == 2) ? (bid >> 1) : bid;
    const int halfbase = (H == 2) ? (bid & 1) * 64 : 0;
    const int g = lane >> 4;
    const int c4 = (lane & 15) * 4;

    const int s = starts[node];
    const int e = starts[node + 1];
    const float* base = x + halfbase + c4;

    f32x4 a = {0.f, 0.f, 0.f, 0.f};
    if (g == 0) a = *reinterpret_cast<const f32x4*>(x + (size_t)node * D + halfbase + c4);

    int j = s;
    for (; j + 8 <= e; j += 8) {
        int i0 = srcs[j + g];
        int i1 = srcs[j + 4 + g];
        f32x4 v0 = *reinterpret_cast<const f32x4*>(base + (size_t)i0 * D);
        f32x4 v1 = *reinterpret_cast<const f32x4*>(base + (size_t)i1 * D);
        a += v0;
        a += v1;
    }
    int eg = j + g;
    if (eg < e) a += *reinterpret_cast<const f32x4*>(base + (size_t)srcs[eg] * D);
    eg += 4;
    if (eg < e) a += *reinterpret_cast<const f32x4*>(base + (size_t)srcs[eg] * D);

    #pragma unroll
    for (int c = 0; c < 4; ++c) {
        a[c] += __shfl_xor(a[c], 16);
        a[c] += __shfl_xor(a[c], 32);
    }

    if (lane < 16) {
        if (BIAS) {
            f32x4 bv = *reinterpret_cast<const f32x4*>(bias + halfbase + c4);
            a += bv;
        }
        const size_t o = (size_t)node * D + halfbase + c4;
        if (PLANES) {
            short h0 = bf16_rne(a[0]);
            short h1 = bf16_rne(a[1]);
            short h2 = bf16_rne(a[2]);
            short h3 = bf16_rne(a[3]);
            short l0 = bf16_rne(a[0] - bf16_f(h0));
            short l1 = bf16_rne(a[1] - bf16_f(h1));
            short l2 = bf16_rne(a[2] - bf16_f(h2));
            short l3 = bf16_rne(a[3] - bf16_f(h3));
            uint2 hw, lw;
            hw.x = (uint32_t)(uint16_t)h0 | ((uint32_t)(uint16_t)h1 << 16);
            hw.y = (uint32_t)(uint16_t)h2 | ((uint32_t)(uint16_t)h3 << 16);
            lw.x = (uint32_t)(uint16_t)l0 | ((uint32_t)(uint16_t)l1 << 16);
            lw.y = (uint32_t)(uint16_t)l2 | ((uint32_t)(uint16_t)l3 << 16);
            *reinterpret_cast<uint2*>(outh + o) = hw;
            *reinterpret_cast<uint2*>(outl + o) = lw;
        } else {
            *reinterpret_cast<f32x4*>(outf + o) = a;
        }
    }
}

// ------------------------- weight split (all 6 in one launch) + cursor zero

struct WsArgs {
    const float* w[6];
    short* hi[6];
    short* lo[6];
    int K[6], Nc[6], base[6];
    int total;
    int* cursor;
    int n;
};

__global__ __launch_bounds__(256) void wsplit_all(WsArgs a) {
    int idx = blockIdx.x * 256 + threadIdx.x;
    int stride = gridDim.x * 256;
    for (int i = idx; i < a.n; i += stride) a.cursor[i] = 0;
    if (idx >= a.total) return;
    int s = 0;
    #pragma unroll
    for (int i = 1; i < 6; ++i)
        if (idx >= a.base[i]) s = i;
    int local = idx - a.base[s];
    int K = a.K[s], Nc = a.Nc[s];
    int n = local / K, k = local - n * K;
    float f = a.w[s][(size_t)k * Nc + n];
    short h = bf16_rne(f);
    a.hi[s][local] = h;
    a.lo[s][local] = bf16_rne(f - bf16_f(h));
}

// ------------------------- GEMM-P: C = planes(A) @ W (+bias) (+stats) ------

template <int DI, int DO, bool STATS, bool BIAS>
__global__ __launch_bounds__(256) void gemm_p(const short* __restrict__ Ah,
                                              const short* __restrict__ Al,
                                              const short* __restrict__ Wh,
                                              const short* __restrict__ Wl,
                                              const float* __restrict__ bias,
                                              float* __restrict__ C,
                                              float* __restrict__ sums, int nrows) {
    constexpr int NF = DO / 16;
    constexpr int KI = DI / 32;
    __shared__ float ssum[DO], sqsum[DO];

    const int t = threadIdx.x;
    if (STATS) {
        if (t < DO) { ssum[t] = 0.f; sqsum[t] = 0.f; }
        __syncthreads();
    }
    const int wave = t >> 6;
    const int lane = t & 63;
    const int lr = lane & 15;
    const int kb = lane >> 4;

    const int row_base = blockIdx.x * 128 + wave * 32;
    const int r0 = row_base + lr;
    const int r1 = r0 + 16;
    const short* a0h = Ah + (size_t)(r0 < nrows ? r0 : 0) * DI + kb * 8;
    const short* a1h = Ah + (size_t)(r1 < nrows ? r1 : 0) * DI + kb * 8;
    const short* a0l = Al + (a0h - Ah);
    const short* a1l = Al + (a1h - Ah);

    f32x4 acc[2][NF];
    #pragma unroll
    for (int m = 0; m < 2; ++m)
        #pragma unroll
        for (int nf = 0; nf < NF; ++nf) acc[m][nf] = f32x4{0.f, 0.f, 0.f, 0.f};

    #pragma unroll
    for (int ki = 0; ki < KI; ++ki) {
        const int k0 = ki * 32;
        bf16x8 ah0 = *reinterpret_cast<const bf16x8*>(a0h + k0);
        bf16x8 al0 = *reinterpret_cast<const bf16x8*>(a0l + k0);
        bf16x8 ah1 = *reinterpret_cast<const bf16x8*>(a1h + k0);
        bf16x8 al1 = *reinterpret_cast<const bf16x8*>(a1l + k0);
        #pragma unroll
        for (int nf = 0; nf < NF; ++nf) {
            const size_t woff = (size_t)(nf * 16 + lr) * DI + k0 + kb * 8;
            bf16x8 bh = *reinterpret_cast<const bf16x8*>(Wh + woff);
            bf16x8 bl = *reinterpret_cast<const bf16x8*>(Wl + woff);
            acc[0][nf] = __builtin_amdgcn_mfma_f32_16x16x32_bf16(ah0, bh, acc[0][nf], 0, 0, 0);
            acc[0][nf] = __builtin_amdgcn_mfma_f32_16x16x32_bf16(al0, bh, acc[0][nf], 0, 0, 0);
            acc[0][nf] = __builtin_amdgcn_mfma_f32_16x16x32_bf16(ah0, bl, acc[0][nf], 0, 0, 0);
            acc[1][nf] = __builtin_amdgcn_mfma_f32_16x16x32_bf16(ah1, bh, acc[1][nf], 0, 0, 0);
            acc[1][nf] = __builtin_amdgcn_mfma_f32_16x16x32_bf16(al1, bh, acc[1][nf], 0, 0, 0);
            acc[1][nf] = __builtin_amdgcn_mfma_f32_16x16x32_bf16(ah1, bl, acc[1][nf], 0, 0, 0);
        }
    }

    #pragma unroll
    for (int nf = 0; nf < NF; ++nf) {
        const int col = nf * 16 + lr;
        const float b = BIAS ? bias[col] : 0.f;
        float s = 0.f, q = 0.f;
        #pragma unroll
        for (int mf = 0; mf < 2; ++mf) {
            const int rbase = row_base + mf * 16 + kb * 4;
            #pragma unroll
            for (int reg = 0; reg < 4; ++reg) {
                const int r = rbase + reg;
                const float val = acc[mf][nf][reg] + b;
                if (r < nrows) {
                    C[(size_t)r * DO + col] = val;
                    if (STATS) {
                        s += val;
                        q = fmaf(val, val, q);
                    }
                }
            }
        }
        if (STATS) {
            s += __shfl_xor(s, 16);
            s += __shfl_xor(s, 32);
            q += __shfl_xor(q, 16);
            q += __shfl_xor(q, 32);
            if (lane < 16) {
                atomicAdd(&ssum[col], s);
                atomicAdd(&sqsum[col], q);
            }
        }
    }
    if (STATS) {
        __syncthreads();
        if (t < DO) {
            atomicAdd(&sums[t], ssum[t]);
            atomicAdd(&sums[DO + t], sqsum[t]);
        }
    }
}

// ------------------------- GEMM-F: C = relu(BN(A)) @ W + bias --------------
// BN finalize inlined: scale/shift computed from raw sums into LDS.

template <int DI, int DO, bool OUTP>
__global__ __launch_bounds__(256) void gemm_f(const float* __restrict__ A,
                                              const short* __restrict__ Wh,
                                              const short* __restrict__ Wl,
                                              const float* __restrict__ bias,
                                              const float* __restrict__ sums,
                                              const float* __restrict__ gvec,
                                              const float* __restrict__ bevec,
                                              float inv_n,
                                              float* __restrict__ Cf,
                                              short* __restrict__ Ch,
                                              short* __restrict__ Cl, int nrows) {
    constexpr int NF = DO / 16;
    constexpr int KI = DI / 32;
    __shared__ float s_scale[DI], s_shift[DI];

    const int t = threadIdx.x;
    if (t < DI) {
        float mu = sums[t] * inv_n;
        float var = sums[DI + t] * inv_n - mu * mu;
        float inv = rsqrtf(var + BN_EPS_F);
        float sc = gvec[t] * inv;
        s_scale[t] = sc;
        s_shift[t] = fmaf(-mu, sc, bevec[t]);
    }
    __syncthreads();

    const int wave = t >> 6;
    const int lane = t & 63;
    const int lr = lane & 15;
    const int kb = lane >> 4;

    const int row_base = blockIdx.x * 128 + wave * 32;
    const int r0 = row_base + lr;
    const int r1 = r0 + 16;
    const float* a0p = A + (size_t)(r0 < nrows ? r0 : 0) * DI + kb * 8;
    const float* a1p = A + (size_t)(r1 < nrows ? r1 : 0) * DI + kb * 8;

    f32x4 acc[2][NF];
    #pragma unroll
    for (int m = 0; m < 2; ++m)
        #pragma unroll
        for (int nf = 0; nf < NF; ++nf) acc[m][nf] = f32x4{0.f, 0.f, 0.f, 0.f};

    #pragma unroll
    for (int ki = 0; ki < KI; ++ki) {
        const int k0 = ki * 32;
        f32x4 a0a = *reinterpret_cast<const f32x4*>(a0p + k0);
        f32x4 a0b = *reinterpret_cast<const f32x4*>(a0p + k0 + 4);
        f32x4 a1a = *reinterpret_cast<const f32x4*>(a1p + k0);
        f32x4 a1b = *reinterpret_cast<const f32x4*>(a1p + k0 + 4);
        {
            const int kk = k0 + kb * 8;
            f32x4 sca = *reinterpret_cast<const f32x4*>(s_scale + kk);
            f32x4 scb = *reinterpret_cast<const f32x4*>(s_scale + kk + 4);
            f32x4 sha = *reinterpret_cast<const f32x4*>(s_shift + kk);
            f32x4 shb = *reinterpret_cast<const f32x4*>(s_shift + kk + 4);
            #pragma unroll
            for (int j = 0; j < 4; ++j) {
                a0a[j] = fmaxf(fmaf(a0a[j], sca[j], sha[j]), 0.f);
                a0b[j] = fmaxf(fmaf(a0b[j], scb[j], shb[j]), 0.f);
                a1a[j] = fmaxf(fmaf(a1a[j], sca[j], sha[j]), 0.f);
                a1b[j] = fmaxf(fmaf(a1b[j], scb[j], shb[j]), 0.f);
            }
        }
        bf16x8 ah0, al0, ah1, al1;
        #pragma unroll
        for (int j = 0; j < 4; ++j) {
            short h;
            h = bf16_rne(a0a[j]); ah0[j] = h;     al0[j] = bf16_rne(a0a[j] - bf16_f(h));
            h = bf16_rne(a0b[j]); ah0[j + 4] = h; al0[j + 4] = bf16_rne(a0b[j] - bf16_f(h));
            h = bf16_rne(a1a[j]); ah1[j] = h;     al1[j] = bf16_rne(a1a[j] - bf16_f(h));
            h = bf16_rne(a1b[j]); ah1[j + 4] = h; al1[j + 4] = bf16_rne(a1b[j] - bf16_f(h));
        }
        #pragma unroll
        for (int nf = 0; nf < NF; ++nf) {
            const size_t woff = (size_t)(nf * 16 + lr) * DI + k0 + kb * 8;
            bf16x8 bh = *reinterpret_cast<const bf16x8*>(Wh + woff);
            bf16x8 bl = *reinterpret_cast<const bf16x8*>(Wl + woff);
            acc[0][nf] = __builtin_amdgcn_mfma_f32_16x16x32_bf16(ah0, bh, acc[0][nf], 0, 0, 0);
            acc[0][nf] = __builtin_amdgcn_mfma_f32_16x16x32_bf16(al0, bh, acc[0][nf], 0, 0, 0);
            acc[0][nf] = __builtin_amdgcn_mfma_f32_16x16x32_bf16(ah0, bl, acc[0][nf], 0, 0, 0);
            acc[1][nf] = __builtin_amdgcn_mfma_f32_16x16x32_bf16(ah1, bh, acc[1][nf], 0, 0, 0);
            acc[1][nf] = __builtin_amdgcn_mfma_f32_16x16x32_bf16(al1, bh, acc[1][nf], 0, 0, 0);
            acc[1][nf] = __builtin_amdgcn_mfma_f32_16x16x32_bf16(ah1, bl, acc[1][nf], 0, 0, 0);
        }
    }

    #pragma unroll
    for (int mf = 0; mf < 2; ++mf) {
        const int rbase = row_base + mf * 16 + kb * 4;
        #pragma unroll
        for (int nf = 0; nf < NF; ++nf) {
            const int col = nf * 16 + lr;
            const float b = bias[col];
            #pragma unroll
            for (int reg = 0; reg < 4; ++reg) {
                const int r = rbase + reg;
                if (r < nrows) {
                    const float val = acc[mf][nf][reg] + b;
                    const size_t idx = (size_t)r * DO + col;
                    if (OUTP) {
                        short h = bf16_rne(val);
                        Ch[idx] = h;
                        Cl[idx] = bf16_rne(val - bf16_f(h));
                    } else {
                        Cf[idx] = val;
                    }
                }
            }
        }
    }
}

// ------------------------- BN stats (used once, layer 2) -------------------

template <int DO>
__global__ __launch_bounds__(256) void stats_kernel(const float* __restrict__ H,
                                                    float* __restrict__ sums, int nrows) {
    constexpr int G = 256 / DO;
    int t = threadIdx.x;
    int col = t % DO;
    int grp = t / DO;
    float s = 0.f, s2 = 0.f;
    for (int r = blockIdx.x * G + grp; r < nrows; r += gridDim.x * G) {
        float v = H[(size_t)r * DO + col];
        s += v;
        s2 = fmaf(v, v, s2);
    }
    __shared__ float sm[256], sm2[256];
    sm[t] = s;
    sm2[t] = s2;
    __syncthreads();
    if (grp == 0) {
        #pragma unroll
        for (int g = 1; g < G; ++g) {
            s += sm[g * DO + col];
            s2 += sm2[g * DO + col];
        }
        atomicAdd(&sums[col], s);
        atomicAdd(&sums[DO + col], s2);
    }
}

// ------------------------- host orchestration ------------------------------

static inline size_t align_up(size_t v, size_t a) { return (v + a - 1) & ~(a - 1); }

extern "C" void kernel_launch(void* const* d_in, const int* in_sizes, int n_in,
                              void* d_out, int out_size, void* d_ws, size_t ws_size,
                              hipStream_t stream) {
    const float* x = (const float*)d_in[0];
    const int* ei = (const int*)d_in[1];
    const int N = in_sizes[0] / 64;
    const int E = in_sizes[1] / 2;
    const int* src = ei;
    const int* dst = ei + E;

    const float* w1[3]; const float* b1[3]; const float* gg[3];
    const float* be[3]; const float* w2[3]; const float* b2[3];
    for (int l = 0; l < 3; ++l) {
        w1[l] = (const float*)d_in[2 + 6 * l + 0];
        b1[l] = (const float*)d_in[2 + 6 * l + 1];
        gg[l] = (const float*)d_in[2 + 6 * l + 2];
        be[l] = (const float*)d_in[2 + 6 * l + 3];
        w2[l] = (const float*)d_in[2 + 6 * l + 4];
        b2[l] = (const float*)d_in[2 + 6 * l + 5];
    }

    char* ws = (char*)d_ws;
    size_t off = 0;
    auto alloc = [&](size_t bytes) {
        void* p = ws + off;
        off = align_up(off + bytes, 64);
        return p;
    };
    float* B0   = (float*)alloc((size_t)N * 128 * 4);   // t0 / t1 / y
    float* B1   = (float*)alloc((size_t)N * 128 * 4);   // h1 / z
    short* PH   = (short*)alloc((size_t)N * 128 * 2);   // pre planes / h2 planes
    short* PL   = (short*)alloc((size_t)N * 128 * 2);
    int* srcs   = (int*)alloc((size_t)E * 4);
    int* starts = (int*)alloc((size_t)(N + 1) * 4);
    int* cursor = (int*)alloc((size_t)N * 4);
    int* bsum   = (int*)alloc(256 * 4);
    float* sums = (float*)alloc(256 * 4);

    const int wdims[6][2] = {{64,128},{128,128},{128,128},{128,128},{128,64},{64,64}};
    const float* wsrc[6] = {w1[0], w2[0], w1[1], w2[1], w1[2], w2[2]};
    short* wh[6]; short* wl[6];
    WsArgs wa;
    int base = 0;
    for (int i = 0; i < 6; ++i) {
        int elems = wdims[i][0] * wdims[i][1];
        wh[i] = (short*)alloc((size_t)elems * 2);
        wl[i] = (short*)alloc((size_t)elems * 2);
        wa.w[i] = wsrc[i]; wa.hi[i] = wh[i]; wa.lo[i] = wl[i];
        wa.K[i] = wdims[i][0]; wa.Nc[i] = wdims[i][1]; wa.base[i] = base;
        base += elems;
    }
    wa.total = base;
    wa.cursor = cursor;
    wa.n = N;
    (void)ws_size; (void)n_in; (void)out_size;

    const float inv_n = 1.0f / (float)N;

    // ---- weight split + cursor zero (one launch) ----
    int wgrid = (N > wa.total ? N : wa.total);
    wsplit_all<<<(wgrid + 255) / 256, 256, 0, stream>>>(wa);

    // ---- CSR build ----
    hist_kernel<<<(E + 255) / 256, 256, 0, stream>>>(dst, cursor, E);
    int chunks = (N + 1023) / 1024;
    scan_part_kernel<<<chunks, 1024, 0, stream>>>(cursor, starts, bsum, N);
    scan_tops_kernel<<<1, 128, 0, stream>>>(bsum, chunks);
    scan_add_kernel<<<chunks, 1024, 0, stream>>>(starts, cursor, bsum, N, E);
    fill_kernel<<<(E + 255) / 256, 256, 0, stream>>>(src, dst, cursor, srcs, E);

    const int nb = (N + 127) / 128;

    // ---- layer 0 ----
    gather_kernel<64, true, false, true><<<N, 64, 0, stream>>>(
        x, starts, srcs, nullptr, nullptr, PH, PL, sums, 256, N);
    gemm_p<64, 128, true, true><<<nb, 256, 0, stream>>>(PH, PL, wh[0], wl[0], b1[0],
                                                        B0, sums, N);
    gemm_f<128, 128, false><<<nb, 256, 0, stream>>>(B0, wh[1], wl[1], b2[0],
                                                    sums, gg[0], be[0], inv_n,
                                                    B1, nullptr, nullptr, N);

    // ---- layer 1 ----
    gather_kernel<128, true, false, true><<<2 * N, 64, 0, stream>>>(
        B1, starts, srcs, nullptr, nullptr, PH, PL, sums, 256, N);
    gemm_p<128, 128, true, true><<<nb, 256, 0, stream>>>(PH, PL, wh[2], wl[2], b1[1],
                                                         B0, sums, N);
    gemm_f<128, 128, true><<<nb, 256, 0, stream>>>(B0, wh[3], wl[3], b2[1],
                                                   sums, gg[1], be[1], inv_n,
                                                   nullptr, PH, PL, N);

    // ---- layer 2 (aggregation commuted through W1) ----
    gemm_p<128, 64, false, false><<<nb, 256, 0, stream>>>(PH, PL, wh[4], wl[4], nullptr,
                                                          B1, nullptr, N);
    gather_kernel<64, false, true, true><<<N, 64, 0, stream>>>(
        B1, starts, srcs, b1[2], B0, nullptr, nullptr, sums, 128, N);
    stats_kernel<64><<<512, 256, 0, stream>>>(B0, sums, N);
    gemm_f<64, 64, false><<<nb, 256, 0, stream>>>(B0, wh[5], wl[5], b2[2],
                                                  sums, gg[2], be[2], inv_n,
                                                  (float*)d_out, nullptr, nullptr, N);
}

// Round 6
// 537.628 us; speedup vs baseline: 1.3688x; 1.0992x over previous
//
#include <hip/hip_runtime.h>
#include <hip/hip_fp16.h>
#include <cstdint>
#include <cstddef>

// ---------------------------------------------------------------------------
// GIN forward:
//  L0: gather_h64(x_h)->planes; gemmP(64->128,+stats); gemmF(fin)->h1 fp16
//  L1: gather_h128(h1_h)->planes; gemmP(128->128,+stats); gemmF(fin)->h2 planes
//  L2: gemmP(128->64)->z fp16; gather_h64(z,+b1)->y f32; stats; gemmF(fin)->out
// Gather inputs are fp16 (halves random-read bytes); accumulation in f32;
// GEMMs use split-bf16 MFMA (3 products) for ~f32 accuracy.
// ---------------------------------------------------------------------------

static constexpr float BN_EPS_F = 1e-5f;

typedef __attribute__((ext_vector_type(8))) short bf16x8;
typedef __attribute__((ext_vector_type(4))) float f32x4;

__device__ __forceinline__ short bf16_rne(float f) {
    uint32_t u = __builtin_bit_cast(uint32_t, f);
    u += 0x7fffu + ((u >> 16) & 1u);
    return (short)(u >> 16);
}
__device__ __forceinline__ float bf16_f(short s) {
    uint32_t u = ((uint32_t)(uint16_t)s) << 16;
    return __builtin_bit_cast(float, u);
}

// ------------------------- CSR build kernels -------------------------------

__global__ __launch_bounds__(256) void hist_kernel(const int* __restrict__ dst,
                                                   int* __restrict__ deg, int E) {
    int e = blockIdx.x * 256 + threadIdx.x;
    if (e < E) atomicAdd(&deg[dst[e]], 1);
}

__global__ __launch_bounds__(1024) void scan_part_kernel(const int* __restrict__ deg,
                                                         int* __restrict__ ex,
                                                         int* __restrict__ bsum, int n) {
    __shared__ int sm[1024];
    int t = threadIdx.x;
    int g = blockIdx.x * 1024 + t;
    int v = (g < n) ? deg[g] : 0;
    sm[t] = v;
    __syncthreads();
    #pragma unroll
    for (int off = 1; off < 1024; off <<= 1) {
        int x = (t >= off) ? sm[t - off] : 0;
        __syncthreads();
        sm[t] += x;
        __syncthreads();
    }
    int incl = sm[t];
    if (g < n) ex[g] = incl - v;
    if (t == 1023) bsum[blockIdx.x] = incl;
}

__global__ __launch_bounds__(128) void scan_tops_kernel(int* __restrict__ bsum, int nb) {
    __shared__ int sm[128];
    int t = threadIdx.x;
    int v = (t < nb) ? bsum[t] : 0;
    sm[t] = v;
    __syncthreads();
    #pragma unroll
    for (int off = 1; off < 128; off <<= 1) {
        int x = (t >= off) ? sm[t - off] : 0;
        __syncthreads();
        sm[t] += x;
        __syncthreads();
    }
    if (t < nb) bsum[t] = sm[t] - v;
}

__global__ __launch_bounds__(1024) void scan_add_kernel(int* __restrict__ starts,
                                                        int* __restrict__ cursor,
                                                        const int* __restrict__ bsum,
                                                        int n, int E) {
    int g = blockIdx.x * 1024 + threadIdx.x;
    if (g < n) {
        int v = starts[g] + bsum[blockIdx.x];
        starts[g] = v;
        cursor[g] = v;
    }
    if (g == 0) starts[n] = E;
}

__global__ __launch_bounds__(256) void fill_kernel(const int* __restrict__ src,
                                                   const int* __restrict__ dst,
                                                   int* __restrict__ cursor,
                                                   int* __restrict__ srcs, int E) {
    int e = blockIdx.x * 256 + threadIdx.x;
    if (e < E) {
        int d = dst[e];
        int p = atomicAdd(&cursor[d], 1);
        srcs[p] = src[e];
    }
}

// ------------------------- gather (fp16 in): out = x + sum_{j} x[src_j] ----
// 1 wave per node. D=64: scalar __half per lane; D=128: __half2 per lane.
// 4-edge unroll; remainder handled with clamped index + masked add so 4 rows
// stay in flight every iteration. OM: 0 = split-bf16 planes, 1 = f32 (+bias).

template <int D, int OM, bool BIAS, bool ZSUMS>
__global__ __launch_bounds__(64) void gather_h(const __half* __restrict__ X,
                                               const int* __restrict__ starts,
                                               const int* __restrict__ srcs,
                                               const float* __restrict__ bias,
                                               short* __restrict__ outh,
                                               short* __restrict__ outl,
                                               float* __restrict__ outf,
                                               float* __restrict__ sums,
                                               int nsum, int n) {
    const int node = blockIdx.x;
    const int lane = threadIdx.x;
    if (ZSUMS && node == 0) {
        for (int i = lane; i < nsum; i += 64) sums[i] = 0.f;
    }
    const int s = starts[node];
    const int e = starts[node + 1];

    if (D == 64) {
        float a = __half2float(X[(size_t)node * 64 + lane]);
        for (int j = s; j < e; j += 4) {
            int i0 = srcs[j];
            int i1 = srcs[(j + 1 < e) ? j + 1 : e - 1];
            int i2 = srcs[(j + 2 < e) ? j + 2 : e - 1];
            int i3 = srcs[(j + 3 < e) ? j + 3 : e - 1];
            float v0 = __half2float(X[(size_t)i0 * 64 + lane]);
            float v1 = __half2float(X[(size_t)i1 * 64 + lane]);
            float v2 = __half2float(X[(size_t)i2 * 64 + lane]);
            float v3 = __half2float(X[(size_t)i3 * 64 + lane]);
            a += v0;
            a += (j + 1 < e) ? v1 : 0.f;
            a += (j + 2 < e) ? v2 : 0.f;
            a += (j + 3 < e) ? v3 : 0.f;
        }
        const size_t o = (size_t)node * 64 + lane;
        if (OM == 0) {
            short h = bf16_rne(a);
            outh[o] = h;
            outl[o] = bf16_rne(a - bf16_f(h));
        } else {
            if (BIAS) a += bias[lane];
            outf[o] = a;
        }
    } else {
        const __half2* X2 = (const __half2*)X;  // row stride D/2 = 64
        float2 a = __half22float2(X2[(size_t)node * 64 + lane]);
        for (int j = s; j < e; j += 4) {
            int i0 = srcs[j];
            int i1 = srcs[(j + 1 < e) ? j + 1 : e - 1];
            int i2 = srcs[(j + 2 < e) ? j + 2 : e - 1];
            int i3 = srcs[(j + 3 < e) ? j + 3 : e - 1];
            float2 v0 = __half22float2(X2[(size_t)i0 * 64 + lane]);
            float2 v1 = __half22float2(X2[(size_t)i1 * 64 + lane]);
            float2 v2 = __half22float2(X2[(size_t)i2 * 64 + lane]);
            float2 v3 = __half22float2(X2[(size_t)i3 * 64 + lane]);
            a.x += v0.x; a.y += v0.y;
            if (j + 1 < e) { a.x += v1.x; a.y += v1.y; }
            if (j + 2 < e) { a.x += v2.x; a.y += v2.y; }
            if (j + 3 < e) { a.x += v3.x; a.y += v3.y; }
        }
        const size_t o = (size_t)node * 128 + 2 * lane;
        if (OM == 0) {
            short h0 = bf16_rne(a.x);
            short h1 = bf16_rne(a.y);
            short l0 = bf16_rne(a.x - bf16_f(h0));
            short l1 = bf16_rne(a.y - bf16_f(h1));
            uint32_t hw = (uint32_t)(uint16_t)h0 | ((uint32_t)(uint16_t)h1 << 16);
            uint32_t lw = (uint32_t)(uint16_t)l0 | ((uint32_t)(uint16_t)l1 << 16);
            *reinterpret_cast<uint32_t*>(outh + o) = hw;
            *reinterpret_cast<uint32_t*>(outl + o) = lw;
        } else {
            if (BIAS) { a.x += bias[2 * lane]; a.y += bias[2 * lane + 1]; }
            outf[o] = a.x;
            outf[o + 1] = a.y;
        }
    }
}

// -------------- weight split + cursor zero + x->fp16 (one launch) ----------

struct WsArgs {
    const float* w[6];
    short* hi[6];
    short* lo[6];
    int K[6], Nc[6], base[6];
    int total;
    int* cursor;
    int n;
    const float* xf;
    __half* xh;
    int nx4;   // N*64/4
};

__global__ __launch_bounds__(256) void wsplit_all(WsArgs a) {
    int idx = blockIdx.x * 256 + threadIdx.x;
    int stride = gridDim.x * 256;
    for (int i = idx; i < a.n; i += stride) a.cursor[i] = 0;
    for (int i = idx; i < a.nx4; i += stride) {
        float4 v = reinterpret_cast<const float4*>(a.xf)[i];
        ushort4 o;
        o.x = __half_as_ushort(__float2half(v.x));
        o.y = __half_as_ushort(__float2half(v.y));
        o.z = __half_as_ushort(__float2half(v.z));
        o.w = __half_as_ushort(__float2half(v.w));
        reinterpret_cast<ushort4*>(a.xh)[i] = o;
    }
    for (int i = idx; i < a.total; i += stride) {
        int s = 0;
        #pragma unroll
        for (int k = 1; k < 6; ++k)
            if (i >= a.base[k]) s = k;
        int local = i - a.base[s];
        int K = a.K[s], Nc = a.Nc[s];
        int nn = local / K, kk = local - nn * K;
        float f = a.w[s][(size_t)kk * Nc + nn];
        short h = bf16_rne(f);
        a.hi[s][local] = h;
        a.lo[s][local] = bf16_rne(f - bf16_f(h));
    }
}

// ------------------------- GEMM-P: C = planes(A) @ W (+bias) (+stats) ------
// OM: 0 = f32 C, 2 = fp16 C.

template <int DI, int DO, bool STATS, bool BIAS, int OM>
__global__ __launch_bounds__(256) void gemm_p(const short* __restrict__ Ah,
                                              const short* __restrict__ Al,
                                              const short* __restrict__ Wh,
                                              const short* __restrict__ Wl,
                                              const float* __restrict__ bias,
                                              float* __restrict__ Cf,
                                              __half* __restrict__ Chh,
                                              float* __restrict__ sums, int nrows) {
    constexpr int NF = DO / 16;
    constexpr int KI = DI / 32;
    __shared__ float ssum[DO], sqsum[DO];

    const int t = threadIdx.x;
    if (STATS) {
        if (t < DO) { ssum[t] = 0.f; sqsum[t] = 0.f; }
        __syncthreads();
    }
    const int wave = t >> 6;
    const int lane = t & 63;
    const int lr = lane & 15;
    const int kb = lane >> 4;

    const int row_base = blockIdx.x * 128 + wave * 32;
    const int r0 = row_base + lr;
    const int r1 = r0 + 16;
    const short* a0h = Ah + (size_t)(r0 < nrows ? r0 : 0) * DI + kb * 8;
    const short* a1h = Ah + (size_t)(r1 < nrows ? r1 : 0) * DI + kb * 8;
    const short* a0l = Al + (a0h - Ah);
    const short* a1l = Al + (a1h - Ah);

    f32x4 acc[2][NF];
    #pragma unroll
    for (int m = 0; m < 2; ++m)
        #pragma unroll
        for (int nf = 0; nf < NF; ++nf) acc[m][nf] = f32x4{0.f, 0.f, 0.f, 0.f};

    #pragma unroll
    for (int ki = 0; ki < KI; ++ki) {
        const int k0 = ki * 32;
        bf16x8 ah0 = *reinterpret_cast<const bf16x8*>(a0h + k0);
        bf16x8 al0 = *reinterpret_cast<const bf16x8*>(a0l + k0);
        bf16x8 ah1 = *reinterpret_cast<const bf16x8*>(a1h + k0);
        bf16x8 al1 = *reinterpret_cast<const bf16x8*>(a1l + k0);
        #pragma unroll
        for (int nf = 0; nf < NF; ++nf) {
            const size_t woff = (size_t)(nf * 16 + lr) * DI + k0 + kb * 8;
            bf16x8 bh = *reinterpret_cast<const bf16x8*>(Wh + woff);
            bf16x8 bl = *reinterpret_cast<const bf16x8*>(Wl + woff);
            acc[0][nf] = __builtin_amdgcn_mfma_f32_16x16x32_bf16(ah0, bh, acc[0][nf], 0, 0, 0);
            acc[0][nf] = __builtin_amdgcn_mfma_f32_16x16x32_bf16(al0, bh, acc[0][nf], 0, 0, 0);
            acc[0][nf] = __builtin_amdgcn_mfma_f32_16x16x32_bf16(ah0, bl, acc[0][nf], 0, 0, 0);
            acc[1][nf] = __builtin_amdgcn_mfma_f32_16x16x32_bf16(ah1, bh, acc[1][nf], 0, 0, 0);
            acc[1][nf] = __builtin_amdgcn_mfma_f32_16x16x32_bf16(al1, bh, acc[1][nf], 0, 0, 0);
            acc[1][nf] = __builtin_amdgcn_mfma_f32_16x16x32_bf16(ah1, bl, acc[1][nf], 0, 0, 0);
        }
    }

    #pragma unroll
    for (int nf = 0; nf < NF; ++nf) {
        const int col = nf * 16 + lr;
        const float b = BIAS ? bias[col] : 0.f;
        float s = 0.f, q = 0.f;
        #pragma unroll
        for (int mf = 0; mf < 2; ++mf) {
            const int rbase = row_base + mf * 16 + kb * 4;
            #pragma unroll
            for (int reg = 0; reg < 4; ++reg) {
                const int r = rbase + reg;
                const float val = acc[mf][nf][reg] + b;
                if (r < nrows) {
                    const size_t idx = (size_t)r * DO + col;
                    if (OM == 2) Chh[idx] = __float2half(val);
                    else Cf[idx] = val;
                    if (STATS) {
                        s += val;
                        q = fmaf(val, val, q);
                    }
                }
            }
        }
        if (STATS) {
            s += __shfl_xor(s, 16);
            s += __shfl_xor(s, 32);
            q += __shfl_xor(q, 16);
            q += __shfl_xor(q, 32);
            if (lane < 16) {
                atomicAdd(&ssum[col], s);
                atomicAdd(&sqsum[col], q);
            }
        }
    }
    if (STATS) {
        __syncthreads();
        if (t < DO) {
            atomicAdd(&sums[t], ssum[t]);
            atomicAdd(&sums[DO + t], sqsum[t]);
        }
    }
}

// ------------------------- GEMM-F: C = relu(BN(A)) @ W + bias --------------
// BN finalize inlined from raw sums. OM: 0 = f32, 1 = planes, 2 = fp16.

template <int DI, int DO, int OM>
__global__ __launch_bounds__(256) void gemm_f(const float* __restrict__ A,
                                              const short* __restrict__ Wh,
                                              const short* __restrict__ Wl,
                                              const float* __restrict__ bias,
                                              const float* __restrict__ sums,
                                              const float* __restrict__ gvec,
                                              const float* __restrict__ bevec,
                                              float inv_n,
                                              float* __restrict__ Cf,
                                              short* __restrict__ Cph,
                                              short* __restrict__ Cpl,
                                              __half* __restrict__ Chh, int nrows) {
    constexpr int NF = DO / 16;
    constexpr int KI = DI / 32;
    __shared__ float s_scale[DI], s_shift[DI];

    const int t = threadIdx.x;
    if (t < DI) {
        float mu = sums[t] * inv_n;
        float var = sums[DI + t] * inv_n - mu * mu;
        float inv = rsqrtf(var + BN_EPS_F);
        float sc = gvec[t] * inv;
        s_scale[t] = sc;
        s_shift[t] = fmaf(-mu, sc, bevec[t]);
    }
    __syncthreads();

    const int wave = t >> 6;
    const int lane = t & 63;
    const int lr = lane & 15;
    const int kb = lane >> 4;

    const int row_base = blockIdx.x * 128 + wave * 32;
    const int r0 = row_base + lr;
    const int r1 = r0 + 16;
    const float* a0p = A + (size_t)(r0 < nrows ? r0 : 0) * DI + kb * 8;
    const float* a1p = A + (size_t)(r1 < nrows ? r1 : 0) * DI + kb * 8;

    f32x4 acc[2][NF];
    #pragma unroll
    for (int m = 0; m < 2; ++m)
        #pragma unroll
        for (int nf = 0; nf < NF; ++nf) acc[m][nf] = f32x4{0.f, 0.f, 0.f, 0.f};

    #pragma unroll
    for (int ki = 0; ki < KI; ++ki) {
        const int k0 = ki * 32;
        f32x4 a0a = *reinterpret_cast<const f32x4*>(a0p + k0);
        f32x4 a0b = *reinterpret_cast<const f32x4*>(a0p + k0 + 4);
        f32x4 a1a = *reinterpret_cast<const f32x4*>(a1p + k0);
        f32x4 a1b = *reinterpret_cast<const f32x4*>(a1p + k0 + 4);
        {
            const int kk = k0 + kb * 8;
            f32x4 sca = *reinterpret_cast<const f32x4*>(s_scale + kk);
            f32x4 scb = *reinterpret_cast<const f32x4*>(s_scale + kk + 4);
            f32x4 sha = *reinterpret_cast<const f32x4*>(s_shift + kk);
            f32x4 shb = *reinterpret_cast<const f32x4*>(s_shift + kk + 4);
            #pragma unroll
            for (int j = 0; j < 4; ++j) {
                a0a[j] = fmaxf(fmaf(a0a[j], sca[j], sha[j]), 0.f);
                a0b[j] = fmaxf(fmaf(a0b[j], scb[j], shb[j]), 0.f);
                a1a[j] = fmaxf(fmaf(a1a[j], sca[j], sha[j]), 0.f);
                a1b[j] = fmaxf(fmaf(a1b[j], scb[j], shb[j]), 0.f);
            }
        }
        bf16x8 ah0, al0, ah1, al1;
        #pragma unroll
        for (int j = 0; j < 4; ++j) {
            short h;
            h = bf16_rne(a0a[j]); ah0[j] = h;     al0[j] = bf16_rne(a0a[j] - bf16_f(h));
            h = bf16_rne(a0b[j]); ah0[j + 4] = h; al0[j + 4] = bf16_rne(a0b[j] - bf16_f(h));
            h = bf16_rne(a1a[j]); ah1[j] = h;     al1[j] = bf16_rne(a1a[j] - bf16_f(h));
            h = bf16_rne(a1b[j]); ah1[j + 4] = h; al1[j + 4] = bf16_rne(a1b[j] - bf16_f(h));
        }
        #pragma unroll
        for (int nf = 0; nf < NF; ++nf) {
            const size_t woff = (size_t)(nf * 16 + lr) * DI + k0 + kb * 8;
            bf16x8 bh = *reinterpret_cast<const bf16x8*>(Wh + woff);
            bf16x8 bl = *reinterpret_cast<const bf16x8*>(Wl + woff);
            acc[0][nf] = __builtin_amdgcn_mfma_f32_16x16x32_bf16(ah0, bh, acc[0][nf], 0, 0, 0);
            acc[0][nf] = __builtin_amdgcn_mfma_f32_16x16x32_bf16(al0, bh, acc[0][nf], 0, 0, 0);
            acc[0][nf] = __builtin_amdgcn_mfma_f32_16x16x32_bf16(ah0, bl, acc[0][nf], 0, 0, 0);
            acc[1][nf] = __builtin_amdgcn_mfma_f32_16x16x32_bf16(ah1, bh, acc[1][nf], 0, 0, 0);
            acc[1][nf] = __builtin_amdgcn_mfma_f32_16x16x32_bf16(al1, bh, acc[1][nf], 0, 0, 0);
            acc[1][nf] = __builtin_amdgcn_mfma_f32_16x16x32_bf16(ah1, bl, acc[1][nf], 0, 0, 0);
        }
    }

    #pragma unroll
    for (int mf = 0; mf < 2; ++mf) {
        const int rbase = row_base + mf * 16 + kb * 4;
        #pragma unroll
        for (int nf = 0; nf < NF; ++nf) {
            const int col = nf * 16 + lr;
            const float b = bias[col];
            #pragma unroll
            for (int reg = 0; reg < 4; ++reg) {
                const int r = rbase + reg;
                if (r < nrows) {
                    const float val = acc[mf][nf][reg] + b;
                    const size_t idx = (size_t)r * DO + col;
                    if (OM == 1) {
                        short h = bf16_rne(val);
                        Cph[idx] = h;
                        Cpl[idx] = bf16_rne(val - bf16_f(h));
                    } else if (OM == 2) {
                        Chh[idx] = __float2half(val);
                    } else {
                        Cf[idx] = val;
                    }
                }
            }
        }
    }
}

// ------------------------- BN stats (used once, layer 2) -------------------

template <int DO>
__global__ __launch_bounds__(256) void stats_kernel(const float* __restrict__ H,
                                                    float* __restrict__ sums, int nrows) {
    constexpr int G = 256 / DO;
    int t = threadIdx.x;
    int col = t % DO;
    int grp = t / DO;
    float s = 0.f, s2 = 0.f;
    for (int r = blockIdx.x * G + grp; r < nrows; r += gridDim.x * G) {
        float v = H[(size_t)r * DO + col];
        s += v;
        s2 = fmaf(v, v, s2);
    }
    __shared__ float sm[256], sm2[256];
    sm[t] = s;
    sm2[t] = s2;
    __syncthreads();
    if (grp == 0) {
        #pragma unroll
        for (int g = 1; g < G; ++g) {
            s += sm[g * DO + col];
            s2 += sm2[g * DO + col];
        }
        atomicAdd(&sums[col], s);
        atomicAdd(&sums[DO + col], s2);
    }
}

// ------------------------- host orchestration ------------------------------

static inline size_t align_up(size_t v, size_t a) { return (v + a - 1) & ~(a - 1); }

extern "C" void kernel_launch(void* const* d_in, const int* in_sizes, int n_in,
                              void* d_out, int out_size, void* d_ws, size_t ws_size,
                              hipStream_t stream) {
    const float* x = (const float*)d_in[0];
    const int* ei = (const int*)d_in[1];
    const int N = in_sizes[0] / 64;
    const int E = in_sizes[1] / 2;
    const int* src = ei;
    const int* dst = ei + E;

    const float* w1[3]; const float* b1[3]; const float* gg[3];
    const float* be[3]; const float* w2[3]; const float* b2[3];
    for (int l = 0; l < 3; ++l) {
        w1[l] = (const float*)d_in[2 + 6 * l + 0];
        b1[l] = (const float*)d_in[2 + 6 * l + 1];
        gg[l] = (const float*)d_in[2 + 6 * l + 2];
        be[l] = (const float*)d_in[2 + 6 * l + 3];
        w2[l] = (const float*)d_in[2 + 6 * l + 4];
        b2[l] = (const float*)d_in[2 + 6 * l + 5];
    }

    char* ws = (char*)d_ws;
    size_t off = 0;
    auto alloc = [&](size_t bytes) {
        void* p = ws + off;
        off = align_up(off + bytes, 64);
        return p;
    };
    float* B0   = (float*)alloc((size_t)N * 128 * 4);   // t0 / t1
    float* B1   = (float*)alloc((size_t)N * 128 * 4);   // h1_h (fp16 alias) / y
    short* PH   = (short*)alloc((size_t)N * 128 * 2);   // pre planes / h2 planes
    short* PL   = (short*)alloc((size_t)N * 128 * 2);
    __half* XH  = (__half*)alloc((size_t)N * 64 * 2);   // x fp16 / z fp16
    int* srcs   = (int*)alloc((size_t)E * 4);
    int* starts = (int*)alloc((size_t)(N + 1) * 4);
    int* cursor = (int*)alloc((size_t)N * 4);
    int* bsum   = (int*)alloc(256 * 4);
    float* sums = (float*)alloc(256 * 4);

    __half* H1H = (__half*)B1;   // h1 fp16 lives in B1 (dead until L2's y)
    __half* ZH  = XH;            // z fp16 reuses x_h (dead after L0 gather)

    const int wdims[6][2] = {{64,128},{128,128},{128,128},{128,128},{128,64},{64,64}};
    const float* wsrc[6] = {w1[0], w2[0], w1[1], w2[1], w1[2], w2[2]};
    short* wh[6]; short* wl[6];
    WsArgs wa;
    int base = 0;
    for (int i = 0; i < 6; ++i) {
        int elems = wdims[i][0] * wdims[i][1];
        wh[i] = (short*)alloc((size_t)elems * 2);
        wl[i] = (short*)alloc((size_t)elems * 2);
        wa.w[i] = wsrc[i]; wa.hi[i] = wh[i]; wa.lo[i] = wl[i];
        wa.K[i] = wdims[i][0]; wa.Nc[i] = wdims[i][1]; wa.base[i] = base;
        base += elems;
    }
    wa.total = base;
    wa.cursor = cursor;
    wa.n = N;
    wa.xf = x;
    wa.xh = XH;
    wa.nx4 = N * 16;
    (void)ws_size; (void)n_in; (void)out_size;

    const float inv_n = 1.0f / (float)N;

    // ---- weight split + cursor zero + x->fp16 (one launch) ----
    int wgrid = wa.nx4;
    if (N > wgrid) wgrid = N;
    if (wa.total > wgrid) wgrid = wa.total;
    wsplit_all<<<(wgrid + 255) / 256, 256, 0, stream>>>(wa);

    // ---- CSR build ----
    hist_kernel<<<(E + 255) / 256, 256, 0, stream>>>(dst, cursor, E);
    int chunks = (N + 1023) / 1024;
    scan_part_kernel<<<chunks, 1024, 0, stream>>>(cursor, starts, bsum, N);
    scan_tops_kernel<<<1, 128, 0, stream>>>(bsum, chunks);
    scan_add_kernel<<<chunks, 1024, 0, stream>>>(starts, cursor, bsum, N, E);
    fill_kernel<<<(E + 255) / 256, 256, 0, stream>>>(src, dst, cursor, srcs, E);

    const int nb = (N + 127) / 128;

    // ---- layer 0 ----
    gather_h<64, 0, false, true><<<N, 64, 0, stream>>>(
        XH, starts, srcs, nullptr, PH, PL, nullptr, sums, 256, N);
    gemm_p<64, 128, true, true, 0><<<nb, 256, 0, stream>>>(
        PH, PL, wh[0], wl[0], b1[0], B0, nullptr, sums, N);
    gemm_f<128, 128, 2><<<nb, 256, 0, stream>>>(
        B0, wh[1], wl[1], b2[0], sums, gg[0], be[0], inv_n,
        nullptr, nullptr, nullptr, H1H, N);

    // ---- layer 1 ----
    gather_h<128, 0, false, true><<<N, 64, 0, stream>>>(
        H1H, starts, srcs, nullptr, PH, PL, nullptr, sums, 256, N);
    gemm_p<128, 128, true, true, 0><<<nb, 256, 0, stream>>>(
        PH, PL, wh[2], wl[2], b1[1], B0, nullptr, sums, N);
    gemm_f<128, 128, 1><<<nb, 256, 0, stream>>>(
        B0, wh[3], wl[3], b2[1], sums, gg[1], be[1], inv_n,
        nullptr, PH, PL, nullptr, N);

    // ---- layer 2 (aggregation commuted through W1) ----
    gemm_p<128, 64, false, false, 2><<<nb, 256, 0, stream>>>(
        PH, PL, wh[4], wl[4], nullptr, nullptr, ZH, nullptr, N);
    gather_h<64, 1, true, true><<<N, 64, 0, stream>>>(
        ZH, starts, srcs, b1[2], nullptr, nullptr, B1, sums, 128, N);
    stats_kernel<64><<<512, 256, 0, stream>>>(B1, sums, N);
    gemm_f<64, 64, 0><<<nb, 256, 0, stream>>>(
        B1, wh[5], wl[5], b2[2], sums, gg[2], be[2], inv_n,
        (float*)d_out, nullptr, nullptr, nullptr, N);
}

// Round 7
// 499.052 us; speedup vs baseline: 1.4746x; 1.0773x over previous
//
#include <hip/hip_runtime.h>
#include <hip/hip_fp16.h>
#include <cstdint>
#include <cstddef>

// ---------------------------------------------------------------------------
// GIN forward, all-fp16 intermediates + split-bf16 MFMA GEMMs:
//  L0: gather64(x_h)->pre0; gemm(64->128,+b1,+stats)->t0; gemm(128->128,BN,+b2)->h1
//  L1: gather128(h1)->pre1; gemm(128->128,+b1,+stats)->t1; gemm(128->128,BN,+b2)->h2
//  L2: gemm(128->64)->z; gather64(z,+b1)->y; stats; gemm(64->64,BN,+b2)->out f32
// (layer-2 aggregation commuted through W1)
// CSR fill is XCD-partitioned (dst-range per blockIdx&7) to kill the 17x
// scatter write amplification across non-coherent per-XCD L2s.
// ---------------------------------------------------------------------------

static constexpr float BN_EPS_F = 1e-5f;

typedef __attribute__((ext_vector_type(8))) short bf16x8;
typedef __attribute__((ext_vector_type(8))) short s16x8;
typedef __attribute__((ext_vector_type(4))) float f32x4;

__device__ __forceinline__ short bf16_rne(float f) {
    uint32_t u = __builtin_bit_cast(uint32_t, f);
    u += 0x7fffu + ((u >> 16) & 1u);
    return (short)(u >> 16);
}
__device__ __forceinline__ float bf16_f(short s) {
    uint32_t u = ((uint32_t)(uint16_t)s) << 16;
    return __builtin_bit_cast(float, u);
}
__device__ __forceinline__ float h2f(short s) {
    return __half2float(__ushort_as_half((unsigned short)s));
}

// ------------------------- CSR build kernels -------------------------------

__global__ __launch_bounds__(256) void hist_kernel(const int* __restrict__ dst,
                                                   int* __restrict__ deg, int E) {
    int e = blockIdx.x * 256 + threadIdx.x;
    if (e < E) atomicAdd(&deg[dst[e]], 1);
}

__global__ __launch_bounds__(1024) void scan_part_kernel(const int* __restrict__ deg,
                                                         int* __restrict__ ex,
                                                         int* __restrict__ bsum, int n) {
    __shared__ int sm[1024];
    int t = threadIdx.x;
    int g = blockIdx.x * 1024 + t;
    int v = (g < n) ? deg[g] : 0;
    sm[t] = v;
    __syncthreads();
    #pragma unroll
    for (int off = 1; off < 1024; off <<= 1) {
        int x = (t >= off) ? sm[t - off] : 0;
        __syncthreads();
        sm[t] += x;
        __syncthreads();
    }
    int incl = sm[t];
    if (g < n) ex[g] = incl - v;
    if (t == 1023) bsum[blockIdx.x] = incl;
}

__global__ __launch_bounds__(128) void scan_tops_kernel(int* __restrict__ bsum, int nb) {
    __shared__ int sm[128];
    int t = threadIdx.x;
    int v = (t < nb) ? bsum[t] : 0;
    sm[t] = v;
    __syncthreads();
    #pragma unroll
    for (int off = 1; off < 128; off <<= 1) {
        int x = (t >= off) ? sm[t - off] : 0;
        __syncthreads();
        sm[t] += x;
        __syncthreads();
    }
    if (t < nb) bsum[t] = sm[t] - v;
}

__global__ __launch_bounds__(1024) void scan_add_kernel(int* __restrict__ starts,
                                                        int* __restrict__ cursor,
                                                        const int* __restrict__ bsum,
                                                        int n, int E) {
    int g = blockIdx.x * 1024 + threadIdx.x;
    if (g < n) {
        int v = starts[g] + bsum[blockIdx.x];
        starts[g] = v;
        cursor[g] = v;
    }
    if (g == 0) starts[n] = E;
}

// XCD-partitioned fill: block b handles dst partition (b&7) over chunk (b>>3).
// Partition r's srcs range is written only by blocks with blockIdx&7==r, which
// the round-robin dispatcher places on XCD r -> full lines assemble in one L2.

__global__ __launch_bounds__(256) void fill_part_kernel(const int* __restrict__ src,
                                                        const int* __restrict__ dst,
                                                        int* __restrict__ cursor,
                                                        int* __restrict__ srcs,
                                                        int E, int P) {
    const unsigned r = blockIdx.x & 7;
    const int chunk = blockIdx.x >> 3;
    const int nchunks = gridDim.x >> 3;
    const int cs = (E + nchunks - 1) / nchunks;
    const int lo = chunk * cs;
    const int hi = (lo + cs < E) ? lo + cs : E;
    for (int e = lo + (int)threadIdx.x; e < hi; e += 256) {
        int d = dst[e];
        unsigned part = (unsigned)d / (unsigned)P;
        if (part > 7u) part = 7u;
        if (part == r) {
            int p = atomicAdd(&cursor[d], 1);
            srcs[p] = src[e];
        }
    }
}

// ------------------------- gather: out_h = x + sum_j x[src_j] (+bias) ------
// 1 wave per node; fp16 in/out; f32 accumulate; 4-edge clamped unroll.

template <int D, bool BIAS, bool ZSUMS>
__global__ __launch_bounds__(64) void gather_hh(const __half* __restrict__ X,
                                                const int* __restrict__ starts,
                                                const int* __restrict__ srcs,
                                                const float* __restrict__ bias,
                                                __half* __restrict__ out,
                                                float* __restrict__ sums,
                                                int nsum, int n) {
    const int node = blockIdx.x;
    const int lane = threadIdx.x;
    if (ZSUMS && node == 0) {
        for (int i = lane; i < nsum; i += 64) sums[i] = 0.f;
    }
    const int s = starts[node];
    const int e = starts[node + 1];

    if (D == 64) {
        float a = __half2float(X[(size_t)node * 64 + lane]);
        for (int j = s; j < e; j += 4) {
            int i0 = srcs[j];
            int i1 = srcs[(j + 1 < e) ? j + 1 : e - 1];
            int i2 = srcs[(j + 2 < e) ? j + 2 : e - 1];
            int i3 = srcs[(j + 3 < e) ? j + 3 : e - 1];
            float v0 = __half2float(X[(size_t)i0 * 64 + lane]);
            float v1 = __half2float(X[(size_t)i1 * 64 + lane]);
            float v2 = __half2float(X[(size_t)i2 * 64 + lane]);
            float v3 = __half2float(X[(size_t)i3 * 64 + lane]);
            a += v0;
            a += (j + 1 < e) ? v1 : 0.f;
            a += (j + 2 < e) ? v2 : 0.f;
            a += (j + 3 < e) ? v3 : 0.f;
        }
        if (BIAS) a += bias[lane];
        out[(size_t)node * 64 + lane] = __float2half(a);
    } else {
        const __half2* X2 = (const __half2*)X;  // row stride 64 half2
        float2 a = __half22float2(X2[(size_t)node * 64 + lane]);
        for (int j = s; j < e; j += 4) {
            int i0 = srcs[j];
            int i1 = srcs[(j + 1 < e) ? j + 1 : e - 1];
            int i2 = srcs[(j + 2 < e) ? j + 2 : e - 1];
            int i3 = srcs[(j + 3 < e) ? j + 3 : e - 1];
            float2 v0 = __half22float2(X2[(size_t)i0 * 64 + lane]);
            float2 v1 = __half22float2(X2[(size_t)i1 * 64 + lane]);
            float2 v2 = __half22float2(X2[(size_t)i2 * 64 + lane]);
            float2 v3 = __half22float2(X2[(size_t)i3 * 64 + lane]);
            a.x += v0.x; a.y += v0.y;
            if (j + 1 < e) { a.x += v1.x; a.y += v1.y; }
            if (j + 2 < e) { a.x += v2.x; a.y += v2.y; }
            if (j + 3 < e) { a.x += v3.x; a.y += v3.y; }
        }
        __half2* O2 = (__half2*)out;
        O2[(size_t)node * 64 + lane] = __floats2half2_rn(a.x, a.y);
    }
}

// -------------- weight split + cursor zero + x->fp16 (one launch) ----------

struct WsArgs {
    const float* w[6];
    short* hi[6];
    short* lo[6];
    int K[6], Nc[6], base[6];
    int total;
    int* cursor;
    int n;
    const float* xf;
    __half* xh;
    int nx4;   // N*64/4
};

__global__ __launch_bounds__(256) void wsplit_all(WsArgs a) {
    int idx = blockIdx.x * 256 + threadIdx.x;
    int stride = gridDim.x * 256;
    for (int i = idx; i < a.n; i += stride) a.cursor[i] = 0;
    for (int i = idx; i < a.nx4; i += stride) {
        float4 v = reinterpret_cast<const float4*>(a.xf)[i];
        ushort4 o;
        o.x = __half_as_ushort(__float2half(v.x));
        o.y = __half_as_ushort(__float2half(v.y));
        o.z = __half_as_ushort(__float2half(v.z));
        o.w = __half_as_ushort(__float2half(v.w));
        reinterpret_cast<ushort4*>(a.xh)[i] = o;
    }
    for (int i = idx; i < a.total; i += stride) {
        int s = 0;
        #pragma unroll
        for (int k = 1; k < 6; ++k)
            if (i >= a.base[k]) s = k;
        int local = i - a.base[s];
        int K = a.K[s], Nc = a.Nc[s];
        int nn = local / K, kk = local - nn * K;
        float f = a.w[s][(size_t)kk * Nc + nn];
        short h = bf16_rne(f);
        a.hi[s][local] = h;
        a.lo[s][local] = bf16_rne(f - bf16_f(h));
    }
}

// ------------------------- unified GEMM ------------------------------------
// C = [relu(BN(A))|A] @ W (+bias) (+stats); A fp16 [N][DI], split to bf16
// hi/lo in-reg (exact for fp16); W pre-split bf16 planes [DO][DI].
// Block: 4 waves x 32 rows = 128 rows.

template <int DI, int DO, bool BN, bool STATS, bool BIAS, bool OUTF16>
__global__ __launch_bounds__(256) void gemm_h(const __half* __restrict__ A,
                                              const short* __restrict__ Wh,
                                              const short* __restrict__ Wl,
                                              const float* __restrict__ bias,
                                              const float* __restrict__ sums_in,
                                              const float* __restrict__ gvec,
                                              const float* __restrict__ bevec,
                                              float inv_n,
                                              float* __restrict__ Cf,
                                              __half* __restrict__ Ch,
                                              float* __restrict__ sums_out, int nrows) {
    constexpr int NF = DO / 16;
    constexpr int KI = DI / 32;
    __shared__ float s_scale[DI], s_shift[DI];
    __shared__ float ssum[DO], sqsum[DO];

    const int t = threadIdx.x;
    if (BN) {
        if (t < DI) {
            float mu = sums_in[t] * inv_n;
            float var = sums_in[DI + t] * inv_n - mu * mu;
            float inv = rsqrtf(var + BN_EPS_F);
            float sc = gvec[t] * inv;
            s_scale[t] = sc;
            s_shift[t] = fmaf(-mu, sc, bevec[t]);
        }
    }
    if (STATS) {
        if (t < DO) { ssum[t] = 0.f; sqsum[t] = 0.f; }
    }
    if (BN || STATS) __syncthreads();

    const int wave = t >> 6;
    const int lane = t & 63;
    const int lr = lane & 15;
    const int kb = lane >> 4;

    const int row_base = blockIdx.x * 128 + wave * 32;
    const int r0 = row_base + lr;
    const int r1 = r0 + 16;
    const short* a0p = (const short*)A + (size_t)(r0 < nrows ? r0 : 0) * DI + kb * 8;
    const short* a1p = (const short*)A + (size_t)(r1 < nrows ? r1 : 0) * DI + kb * 8;

    f32x4 acc[2][NF];
    #pragma unroll
    for (int m = 0; m < 2; ++m)
        #pragma unroll
        for (int nf = 0; nf < NF; ++nf) acc[m][nf] = f32x4{0.f, 0.f, 0.f, 0.f};

    #pragma unroll
    for (int ki = 0; ki < KI; ++ki) {
        const int k0 = ki * 32;
        s16x8 u0 = *reinterpret_cast<const s16x8*>(a0p + k0);
        s16x8 u1 = *reinterpret_cast<const s16x8*>(a1p + k0);
        float av0[8], av1[8];
        #pragma unroll
        for (int j = 0; j < 8; ++j) {
            av0[j] = h2f(u0[j]);
            av1[j] = h2f(u1[j]);
        }
        if (BN) {
            const int kk = k0 + kb * 8;
            #pragma unroll
            for (int j = 0; j < 8; ++j) {
                float sc = s_scale[kk + j];
                float sh = s_shift[kk + j];
                av0[j] = fmaxf(fmaf(av0[j], sc, sh), 0.f);
                av1[j] = fmaxf(fmaf(av1[j], sc, sh), 0.f);
            }
        }
        bf16x8 ah0, al0, ah1, al1;
        #pragma unroll
        for (int j = 0; j < 8; ++j) {
            short h;
            h = bf16_rne(av0[j]); ah0[j] = h; al0[j] = bf16_rne(av0[j] - bf16_f(h));
            h = bf16_rne(av1[j]); ah1[j] = h; al1[j] = bf16_rne(av1[j] - bf16_f(h));
        }
        #pragma unroll
        for (int nf = 0; nf < NF; ++nf) {
            const size_t woff = (size_t)(nf * 16 + lr) * DI + k0 + kb * 8;
            bf16x8 bh = *reinterpret_cast<const bf16x8*>(Wh + woff);
            bf16x8 bl = *reinterpret_cast<const bf16x8*>(Wl + woff);
            acc[0][nf] = __builtin_amdgcn_mfma_f32_16x16x32_bf16(ah0, bh, acc[0][nf], 0, 0, 0);
            acc[0][nf] = __builtin_amdgcn_mfma_f32_16x16x32_bf16(al0, bh, acc[0][nf], 0, 0, 0);
            acc[0][nf] = __builtin_amdgcn_mfma_f32_16x16x32_bf16(ah0, bl, acc[0][nf], 0, 0, 0);
            acc[1][nf] = __builtin_amdgcn_mfma_f32_16x16x32_bf16(ah1, bh, acc[1][nf], 0, 0, 0);
            acc[1][nf] = __builtin_amdgcn_mfma_f32_16x16x32_bf16(al1, bh, acc[1][nf], 0, 0, 0);
            acc[1][nf] = __builtin_amdgcn_mfma_f32_16x16x32_bf16(ah1, bl, acc[1][nf], 0, 0, 0);
        }
    }

    #pragma unroll
    for (int nf = 0; nf < NF; ++nf) {
        const int col = nf * 16 + lr;
        const float b = BIAS ? bias[col] : 0.f;
        float s = 0.f, q = 0.f;
        #pragma unroll
        for (int mf = 0; mf < 2; ++mf) {
            const int rbase = row_base + mf * 16 + kb * 4;
            #pragma unroll
            for (int reg = 0; reg < 4; ++reg) {
                const int r = rbase + reg;
                const float val = acc[mf][nf][reg] + b;
                if (r < nrows) {
                    const size_t idx = (size_t)r * DO + col;
                    if (OUTF16) Ch[idx] = __float2half(val);
                    else Cf[idx] = val;
                    if (STATS) {
                        s += val;
                        q = fmaf(val, val, q);
                    }
                }
            }
        }
        if (STATS) {
            s += __shfl_xor(s, 16);
            s += __shfl_xor(s, 32);
            q += __shfl_xor(q, 16);
            q += __shfl_xor(q, 32);
            if (lane < 16) {
                atomicAdd(&ssum[col], s);
                atomicAdd(&sqsum[col], q);
            }
        }
    }
    if (STATS) {
        __syncthreads();
        if (t < DO) {
            atomicAdd(&sums_out[t], ssum[t]);
            atomicAdd(&sums_out[DO + t], sqsum[t]);
        }
    }
}

// ------------------------- BN stats over fp16 (layer 2) --------------------

template <int DO>
__global__ __launch_bounds__(256) void stats_h(const __half* __restrict__ H,
                                               float* __restrict__ sums, int nrows) {
    constexpr int G = 256 / DO;
    int t = threadIdx.x;
    int col = t % DO;
    int grp = t / DO;
    float s = 0.f, s2 = 0.f;
    for (int r = blockIdx.x * G + grp; r < nrows; r += gridDim.x * G) {
        float v = __half2float(H[(size_t)r * DO + col]);
        s += v;
        s2 = fmaf(v, v, s2);
    }
    __shared__ float sm[256], sm2[256];
    sm[t] = s;
    sm2[t] = s2;
    __syncthreads();
    if (grp == 0) {
        #pragma unroll
        for (int g = 1; g < G; ++g) {
            s += sm[g * DO + col];
            s2 += sm2[g * DO + col];
        }
        atomicAdd(&sums[col], s);
        atomicAdd(&sums[DO + col], s2);
    }
}

// ------------------------- host orchestration ------------------------------

static inline size_t align_up(size_t v, size_t a) { return (v + a - 1) & ~(a - 1); }

extern "C" void kernel_launch(void* const* d_in, const int* in_sizes, int n_in,
                              void* d_out, int out_size, void* d_ws, size_t ws_size,
                              hipStream_t stream) {
    const float* x = (const float*)d_in[0];
    const int* ei = (const int*)d_in[1];
    const int N = in_sizes[0] / 64;
    const int E = in_sizes[1] / 2;
    const int* src = ei;
    const int* dst = ei + E;

    const float* w1[3]; const float* b1[3]; const float* gg[3];
    const float* be[3]; const float* w2[3]; const float* b2[3];
    for (int l = 0; l < 3; ++l) {
        w1[l] = (const float*)d_in[2 + 6 * l + 0];
        b1[l] = (const float*)d_in[2 + 6 * l + 1];
        gg[l] = (const float*)d_in[2 + 6 * l + 2];
        be[l] = (const float*)d_in[2 + 6 * l + 3];
        w2[l] = (const float*)d_in[2 + 6 * l + 4];
        b2[l] = (const float*)d_in[2 + 6 * l + 5];
    }

    char* ws = (char*)d_ws;
    size_t off = 0;
    auto alloc = [&](size_t bytes) {
        void* p = ws + off;
        off = align_up(off + bytes, 64);
        return p;
    };
    __half* HA   = (__half*)alloc((size_t)N * 128 * 2);  // t0 / pre1 / h2
    __half* HB   = (__half*)alloc((size_t)N * 128 * 2);  // h1 / t1
    __half* XH   = (__half*)alloc((size_t)N * 64 * 2);   // x fp16, later z
    __half* PRE0 = (__half*)alloc((size_t)N * 64 * 2);   // pre0, later y
    int* srcs   = (int*)alloc((size_t)E * 4);
    int* starts = (int*)alloc((size_t)(N + 1) * 4);
    int* cursor = (int*)alloc((size_t)N * 4);
    int* bsum   = (int*)alloc(256 * 4);
    float* sums = (float*)alloc(256 * 4);

    const int wdims[6][2] = {{64,128},{128,128},{128,128},{128,128},{128,64},{64,64}};
    const float* wsrc[6] = {w1[0], w2[0], w1[1], w2[1], w1[2], w2[2]};
    short* wh[6]; short* wl[6];
    WsArgs wa;
    int base = 0;
    for (int i = 0; i < 6; ++i) {
        int elems = wdims[i][0] * wdims[i][1];
        wh[i] = (short*)alloc((size_t)elems * 2);
        wl[i] = (short*)alloc((size_t)elems * 2);
        wa.w[i] = wsrc[i]; wa.hi[i] = wh[i]; wa.lo[i] = wl[i];
        wa.K[i] = wdims[i][0]; wa.Nc[i] = wdims[i][1]; wa.base[i] = base;
        base += elems;
    }
    wa.total = base;
    wa.cursor = cursor;
    wa.n = N;
    wa.xf = x;
    wa.xh = XH;
    wa.nx4 = N * 16;
    (void)ws_size; (void)n_in; (void)out_size;

    const float inv_n = 1.0f / (float)N;

    // ---- weight split + cursor zero + x->fp16 ----
    int wgrid = wa.nx4;
    if (N > wgrid) wgrid = N;
    if (wa.total > wgrid) wgrid = wa.total;
    wsplit_all<<<(wgrid + 255) / 256, 256, 0, stream>>>(wa);

    // ---- CSR build ----
    hist_kernel<<<(E + 255) / 256, 256, 0, stream>>>(dst, cursor, E);
    int chunks = (N + 1023) / 1024;
    scan_part_kernel<<<chunks, 1024, 0, stream>>>(cursor, starts, bsum, N);
    scan_tops_kernel<<<1, 128, 0, stream>>>(bsum, chunks);
    scan_add_kernel<<<chunks, 1024, 0, stream>>>(starts, cursor, bsum, N, E);
    int P = N / 8;
    if (P < 1) P = 1;
    fill_part_kernel<<<1024, 256, 0, stream>>>(src, dst, cursor, srcs, E, P);

    const int nb = (N + 127) / 128;

    // ---- layer 0 ----
    gather_hh<64, false, true><<<N, 64, 0, stream>>>(
        XH, starts, srcs, nullptr, PRE0, sums, 256, N);
    gemm_h<64, 128, false, true, true, true><<<nb, 256, 0, stream>>>(
        PRE0, wh[0], wl[0], b1[0], nullptr, nullptr, nullptr, inv_n,
        nullptr, HA, sums, N);
    gemm_h<128, 128, true, false, true, true><<<nb, 256, 0, stream>>>(
        HA, wh[1], wl[1], b2[0], sums, gg[0], be[0], inv_n,
        nullptr, HB, nullptr, N);

    // ---- layer 1 ----
    gather_hh<128, false, true><<<N, 64, 0, stream>>>(
        HB, starts, srcs, nullptr, HA, sums, 256, N);
    gemm_h<128, 128, false, true, true, true><<<nb, 256, 0, stream>>>(
        HA, wh[2], wl[2], b1[1], nullptr, nullptr, nullptr, inv_n,
        nullptr, HB, sums, N);
    gemm_h<128, 128, true, false, true, true><<<nb, 256, 0, stream>>>(
        HB, wh[3], wl[3], b2[1], sums, gg[1], be[1], inv_n,
        nullptr, HA, nullptr, N);

    // ---- layer 2 (aggregation commuted through W1) ----
    gemm_h<128, 64, false, false, false, true><<<nb, 256, 0, stream>>>(
        HA, wh[4], wl[4], nullptr, nullptr, nullptr, nullptr, inv_n,
        nullptr, XH, nullptr, N);
    gather_hh<64, true, true><<<N, 64, 0, stream>>>(
        XH, starts, srcs, b1[2], PRE0, sums, 128, N);
    stats_h<64><<<512, 256, 0, stream>>>(PRE0, sums, N);
    gemm_h<64, 64, true, false, true, false><<<nb, 256, 0, stream>>>(
        PRE0, wh[5], wl[5], b2[2], sums, gg[2], be[2], inv_n,
        (float*)d_out, nullptr, nullptr, N);
}

// Round 8
// 465.906 us; speedup vs baseline: 1.5795x; 1.0711x over previous
//
#include <hip/hip_runtime.h>
#include <hip/hip_fp16.h>
#include <cstdint>
#include <cstddef>

// ---------------------------------------------------------------------------
// GIN forward, all-fp16 intermediates, fp16 MFMA GEMMs with split-fp16 W:
//  L0: gather64(x_h)->pre0; gemm(64->128,+b1,+stats)->t0; gemm(128->128,BN,+b2)->h1
//  L1: gather128(h1)->pre1; gemm(128->128,+b1,+stats)->t1; gemm(128->128,BN,+b2)->h2
//  L2: gemm(128->64)->z; gather64(z,+b1)->y; stats; gemm(64->64,BN,+b2)->out f32
// A fp16 feeds mfma_f32_16x16x32_f16 directly (exact); W = Wh+Wl fp16 planes
// (2 MFMAs/fragment, ~22-bit effective W mantissa). DO=128 GEMMs are split
// into two 64-col block-columns for occupancy.
// ---------------------------------------------------------------------------

static constexpr float BN_EPS_F = 1e-5f;

typedef __attribute__((ext_vector_type(8))) _Float16 f16x8;
typedef __attribute__((ext_vector_type(4))) float f32x4;

// ------------------------- CSR build kernels -------------------------------

__global__ __launch_bounds__(256) void hist_kernel(const int* __restrict__ dst,
                                                   int* __restrict__ deg, int E) {
    int e = blockIdx.x * 256 + threadIdx.x;
    if (e < E) atomicAdd(&deg[dst[e]], 1);
}

__global__ __launch_bounds__(1024) void scan_part_kernel(const int* __restrict__ deg,
                                                         int* __restrict__ ex,
                                                         int* __restrict__ bsum, int n) {
    __shared__ int sm[1024];
    int t = threadIdx.x;
    int g = blockIdx.x * 1024 + t;
    int v = (g < n) ? deg[g] : 0;
    sm[t] = v;
    __syncthreads();
    #pragma unroll
    for (int off = 1; off < 1024; off <<= 1) {
        int x = (t >= off) ? sm[t - off] : 0;
        __syncthreads();
        sm[t] += x;
        __syncthreads();
    }
    int incl = sm[t];
    if (g < n) ex[g] = incl - v;
    if (t == 1023) bsum[blockIdx.x] = incl;
}

__global__ __launch_bounds__(128) void scan_tops_kernel(int* __restrict__ bsum, int nb) {
    __shared__ int sm[128];
    int t = threadIdx.x;
    int v = (t < nb) ? bsum[t] : 0;
    sm[t] = v;
    __syncthreads();
    #pragma unroll
    for (int off = 1; off < 128; off <<= 1) {
        int x = (t >= off) ? sm[t - off] : 0;
        __syncthreads();
        sm[t] += x;
        __syncthreads();
    }
    if (t < nb) bsum[t] = sm[t] - v;
}

__global__ __launch_bounds__(1024) void scan_add_kernel(int* __restrict__ starts,
                                                        int* __restrict__ cursor,
                                                        const int* __restrict__ bsum,
                                                        int n, int E) {
    int g = blockIdx.x * 1024 + threadIdx.x;
    if (g < n) {
        int v = starts[g] + bsum[blockIdx.x];
        starts[g] = v;
        cursor[g] = v;
    }
    if (g == 0) starts[n] = E;
}

// XCD-partitioned fill (kills cross-XCD scatter write amplification).

__global__ __launch_bounds__(256) void fill_part_kernel(const int* __restrict__ src,
                                                        const int* __restrict__ dst,
                                                        int* __restrict__ cursor,
                                                        int* __restrict__ srcs,
                                                        int E, int P) {
    const unsigned r = blockIdx.x & 7;
    const int chunk = blockIdx.x >> 3;
    const int nchunks = gridDim.x >> 3;
    const int cs = (E + nchunks - 1) / nchunks;
    const int lo = chunk * cs;
    const int hi = (lo + cs < E) ? lo + cs : E;
    for (int e = lo + (int)threadIdx.x; e < hi; e += 256) {
        int d = dst[e];
        unsigned part = (unsigned)d / (unsigned)P;
        if (part > 7u) part = 7u;
        if (part == r) {
            int p = atomicAdd(&cursor[d], 1);
            srcs[p] = src[e];
        }
    }
}

// ------------------------- gather: out_h = x + sum_j x[src_j] (+bias) ------
// 1 wave per node; fp16 in/out; f32 accumulate; 4-edge clamped unroll.

template <int D, bool BIAS, bool ZSUMS>
__global__ __launch_bounds__(64) void gather_hh(const __half* __restrict__ X,
                                                const int* __restrict__ starts,
                                                const int* __restrict__ srcs,
                                                const float* __restrict__ bias,
                                                __half* __restrict__ out,
                                                float* __restrict__ sums,
                                                int nsum, int n) {
    const int node = blockIdx.x;
    const int lane = threadIdx.x;
    if (ZSUMS && node == 0) {
        for (int i = lane; i < nsum; i += 64) sums[i] = 0.f;
    }
    const int s = starts[node];
    const int e = starts[node + 1];

    if (D == 64) {
        float a = __half2float(X[(size_t)node * 64 + lane]);
        for (int j = s; j < e; j += 4) {
            int i0 = srcs[j];
            int i1 = srcs[(j + 1 < e) ? j + 1 : e - 1];
            int i2 = srcs[(j + 2 < e) ? j + 2 : e - 1];
            int i3 = srcs[(j + 3 < e) ? j + 3 : e - 1];
            float v0 = __half2float(X[(size_t)i0 * 64 + lane]);
            float v1 = __half2float(X[(size_t)i1 * 64 + lane]);
            float v2 = __half2float(X[(size_t)i2 * 64 + lane]);
            float v3 = __half2float(X[(size_t)i3 * 64 + lane]);
            a += v0;
            a += (j + 1 < e) ? v1 : 0.f;
            a += (j + 2 < e) ? v2 : 0.f;
            a += (j + 3 < e) ? v3 : 0.f;
        }
        if (BIAS) a += bias[lane];
        out[(size_t)node * 64 + lane] = __float2half(a);
    } else {
        const __half2* X2 = (const __half2*)X;  // row stride 64 half2
        float2 a = __half22float2(X2[(size_t)node * 64 + lane]);
        for (int j = s; j < e; j += 4) {
            int i0 = srcs[j];
            int i1 = srcs[(j + 1 < e) ? j + 1 : e - 1];
            int i2 = srcs[(j + 2 < e) ? j + 2 : e - 1];
            int i3 = srcs[(j + 3 < e) ? j + 3 : e - 1];
            float2 v0 = __half22float2(X2[(size_t)i0 * 64 + lane]);
            float2 v1 = __half22float2(X2[(size_t)i1 * 64 + lane]);
            float2 v2 = __half22float2(X2[(size_t)i2 * 64 + lane]);
            float2 v3 = __half22float2(X2[(size_t)i3 * 64 + lane]);
            a.x += v0.x; a.y += v0.y;
            if (j + 1 < e) { a.x += v1.x; a.y += v1.y; }
            if (j + 2 < e) { a.x += v2.x; a.y += v2.y; }
            if (j + 3 < e) { a.x += v3.x; a.y += v3.y; }
        }
        __half2* O2 = (__half2*)out;
        O2[(size_t)node * 64 + lane] = __floats2half2_rn(a.x, a.y);
    }
}

// -------- weight split (fp16 hi/lo) + cursor zero + x->fp16 (one launch) ---

struct WsArgs {
    const float* w[6];
    short* hi[6];
    short* lo[6];
    int K[6], Nc[6], base[6];
    int total;
    int* cursor;
    int n;
    const float* xf;
    __half* xh;
    int nx4;   // N*64/4
};

__global__ __launch_bounds__(256) void wsplit_all(WsArgs a) {
    int idx = blockIdx.x * 256 + threadIdx.x;
    int stride = gridDim.x * 256;
    for (int i = idx; i < a.n; i += stride) a.cursor[i] = 0;
    for (int i = idx; i < a.nx4; i += stride) {
        float4 v = reinterpret_cast<const float4*>(a.xf)[i];
        ushort4 o;
        o.x = __half_as_ushort(__float2half(v.x));
        o.y = __half_as_ushort(__float2half(v.y));
        o.z = __half_as_ushort(__float2half(v.z));
        o.w = __half_as_ushort(__float2half(v.w));
        reinterpret_cast<ushort4*>(a.xh)[i] = o;
    }
    for (int i = idx; i < a.total; i += stride) {
        int s = 0;
        #pragma unroll
        for (int k = 1; k < 6; ++k)
            if (i >= a.base[k]) s = k;
        int local = i - a.base[s];
        int K = a.K[s], Nc = a.Nc[s];
        int nn = local / K, kk = local - nn * K;
        float f = a.w[s][(size_t)kk * Nc + nn];
        __half h = __float2half(f);
        a.hi[s][local] = (short)__half_as_ushort(h);
        a.lo[s][local] = (short)__half_as_ushort(__float2half(f - __half2float(h)));
    }
}

// ------------------------- fp16 MFMA GEMM ----------------------------------
// C = [relu(BN(A))|A] @ (Wh+Wl) (+bias) (+stats); A fp16 [N][DI] feeds
// mfma_f32_16x16x32_f16 directly; W planes fp16 [DO][DI].
// Block: 4 waves x 32 rows = 128 rows x 64 cols; grid = nbrow * (DO/64).

template <int DI, int DO, bool BN, bool STATS, bool BIAS, bool OUTF16>
__global__ __launch_bounds__(256) void gemm16(const __half* __restrict__ A,
                                              const short* __restrict__ Wh,
                                              const short* __restrict__ Wl,
                                              const float* __restrict__ bias,
                                              const float* __restrict__ sums_in,
                                              const float* __restrict__ gvec,
                                              const float* __restrict__ bevec,
                                              float inv_n,
                                              float* __restrict__ Cf,
                                              __half* __restrict__ Ch,
                                              float* __restrict__ sums_out, int nrows) {
    constexpr int CT = DO / 64;   // column tiles per row-chunk
    constexpr int KI = DI / 32;
    __shared__ float s_scale[DI], s_shift[DI];
    __shared__ float ssum[64], sqsum[64];

    const int t = threadIdx.x;
    if (BN) {
        if (t < DI) {
            float mu = sums_in[t] * inv_n;
            float var = sums_in[DI + t] * inv_n - mu * mu;
            float inv = rsqrtf(var + BN_EPS_F);
            float sc = gvec[t] * inv;
            s_scale[t] = sc;
            s_shift[t] = fmaf(-mu, sc, bevec[t]);
        }
    }
    if (STATS) {
        if (t < 64) { ssum[t] = 0.f; sqsum[t] = 0.f; }
    }
    if (BN || STATS) __syncthreads();

    const int rowblk = blockIdx.x / CT;
    const int colbase = (blockIdx.x % CT) * 64;
    const int wave = t >> 6;
    const int lane = t & 63;
    const int lr = lane & 15;
    const int kb = lane >> 4;

    const int row_base = rowblk * 128 + wave * 32;
    const int r0 = row_base + lr;
    const int r1 = r0 + 16;
    const _Float16* a0p = (const _Float16*)A + (size_t)(r0 < nrows ? r0 : 0) * DI + kb * 8;
    const _Float16* a1p = (const _Float16*)A + (size_t)(r1 < nrows ? r1 : 0) * DI + kb * 8;
    const _Float16* whp = (const _Float16*)Wh;
    const _Float16* wlp = (const _Float16*)Wl;

    f32x4 acc[2][4];
    #pragma unroll
    for (int m = 0; m < 2; ++m)
        #pragma unroll
        for (int nf = 0; nf < 4; ++nf) acc[m][nf] = f32x4{0.f, 0.f, 0.f, 0.f};

    #pragma unroll
    for (int ki = 0; ki < KI; ++ki) {
        const int k0 = ki * 32;
        f16x8 a0 = *reinterpret_cast<const f16x8*>(a0p + k0);
        f16x8 a1 = *reinterpret_cast<const f16x8*>(a1p + k0);
        if (BN) {
            const int kk = k0 + kb * 8;
            #pragma unroll
            for (int j = 0; j < 8; ++j) {
                float sc = s_scale[kk + j];
                float sh = s_shift[kk + j];
                a0[j] = (_Float16)fmaxf(fmaf((float)a0[j], sc, sh), 0.f);
                a1[j] = (_Float16)fmaxf(fmaf((float)a1[j], sc, sh), 0.f);
            }
        }
        #pragma unroll
        for (int nf = 0; nf < 4; ++nf) {
            const size_t woff = (size_t)(colbase + nf * 16 + lr) * DI + k0 + kb * 8;
            f16x8 bh = *reinterpret_cast<const f16x8*>(whp + woff);
            f16x8 bl = *reinterpret_cast<const f16x8*>(wlp + woff);
            acc[0][nf] = __builtin_amdgcn_mfma_f32_16x16x32_f16(a0, bh, acc[0][nf], 0, 0, 0);
            acc[0][nf] = __builtin_amdgcn_mfma_f32_16x16x32_f16(a0, bl, acc[0][nf], 0, 0, 0);
            acc[1][nf] = __builtin_amdgcn_mfma_f32_16x16x32_f16(a1, bh, acc[1][nf], 0, 0, 0);
            acc[1][nf] = __builtin_amdgcn_mfma_f32_16x16x32_f16(a1, bl, acc[1][nf], 0, 0, 0);
        }
    }

    #pragma unroll
    for (int nf = 0; nf < 4; ++nf) {
        const int lcol = nf * 16 + lr;
        const int col = colbase + lcol;
        const float b = BIAS ? bias[col] : 0.f;
        float s = 0.f, q = 0.f;
        #pragma unroll
        for (int mf = 0; mf < 2; ++mf) {
            const int rbase = row_base + mf * 16 + kb * 4;
            #pragma unroll
            for (int reg = 0; reg < 4; ++reg) {
                const int r = rbase + reg;
                const float val = acc[mf][nf][reg] + b;
                if (r < nrows) {
                    const size_t idx = (size_t)r * DO + col;
                    if (OUTF16) Ch[idx] = __float2half(val);
                    else Cf[idx] = val;
                    if (STATS) {
                        s += val;
                        q = fmaf(val, val, q);
                    }
                }
            }
        }
        if (STATS) {
            s += __shfl_xor(s, 16);
            s += __shfl_xor(s, 32);
            q += __shfl_xor(q, 16);
            q += __shfl_xor(q, 32);
            if (lane < 16) {
                atomicAdd(&ssum[lcol], s);
                atomicAdd(&sqsum[lcol], q);
            }
        }
    }
    if (STATS) {
        __syncthreads();
        if (t < 64) {
            atomicAdd(&sums_out[colbase + t], ssum[t]);
            atomicAdd(&sums_out[DO + colbase + t], sqsum[t]);
        }
    }
}

// ------------------------- BN stats over fp16 (layer 2) --------------------

template <int DO>
__global__ __launch_bounds__(256) void stats_h(const __half* __restrict__ H,
                                               float* __restrict__ sums, int nrows) {
    constexpr int G = 256 / DO;
    int t = threadIdx.x;
    int col = t % DO;
    int grp = t / DO;
    float s = 0.f, s2 = 0.f;
    for (int r = blockIdx.x * G + grp; r < nrows; r += gridDim.x * G) {
        float v = __half2float(H[(size_t)r * DO + col]);
        s += v;
        s2 = fmaf(v, v, s2);
    }
    __shared__ float sm[256], sm2[256];
    sm[t] = s;
    sm2[t] = s2;
    __syncthreads();
    if (grp == 0) {
        #pragma unroll
        for (int g = 1; g < G; ++g) {
            s += sm[g * DO + col];
            s2 += sm2[g * DO + col];
        }
        atomicAdd(&sums[col], s);
        atomicAdd(&sums[DO + col], s2);
    }
}

// ------------------------- host orchestration ------------------------------

static inline size_t align_up(size_t v, size_t a) { return (v + a - 1) & ~(a - 1); }

extern "C" void kernel_launch(void* const* d_in, const int* in_sizes, int n_in,
                              void* d_out, int out_size, void* d_ws, size_t ws_size,
                              hipStream_t stream) {
    const float* x = (const float*)d_in[0];
    const int* ei = (const int*)d_in[1];
    const int N = in_sizes[0] / 64;
    const int E = in_sizes[1] / 2;
    const int* src = ei;
    const int* dst = ei + E;

    const float* w1[3]; const float* b1[3]; const float* gg[3];
    const float* be[3]; const float* w2[3]; const float* b2[3];
    for (int l = 0; l < 3; ++l) {
        w1[l] = (const float*)d_in[2 + 6 * l + 0];
        b1[l] = (const float*)d_in[2 + 6 * l + 1];
        gg[l] = (const float*)d_in[2 + 6 * l + 2];
        be[l] = (const float*)d_in[2 + 6 * l + 3];
        w2[l] = (const float*)d_in[2 + 6 * l + 4];
        b2[l] = (const float*)d_in[2 + 6 * l + 5];
    }

    char* ws = (char*)d_ws;
    size_t off = 0;
    auto alloc = [&](size_t bytes) {
        void* p = ws + off;
        off = align_up(off + bytes, 64);
        return p;
    };
    __half* HA   = (__half*)alloc((size_t)N * 128 * 2);  // t0 / pre1 / h2
    __half* HB   = (__half*)alloc((size_t)N * 128 * 2);  // h1 / t1
    __half* XH   = (__half*)alloc((size_t)N * 64 * 2);   // x fp16, later z
    __half* PRE0 = (__half*)alloc((size_t)N * 64 * 2);   // pre0, later y
    int* srcs   = (int*)alloc((size_t)E * 4);
    int* starts = (int*)alloc((size_t)(N + 1) * 4);
    int* cursor = (int*)alloc((size_t)N * 4);
    int* bsum   = (int*)alloc(256 * 4);
    float* sums = (float*)alloc(256 * 4);

    const int wdims[6][2] = {{64,128},{128,128},{128,128},{128,128},{128,64},{64,64}};
    const float* wsrc[6] = {w1[0], w2[0], w1[1], w2[1], w1[2], w2[2]};
    short* wh[6]; short* wl[6];
    WsArgs wa;
    int base = 0;
    for (int i = 0; i < 6; ++i) {
        int elems = wdims[i][0] * wdims[i][1];
        wh[i] = (short*)alloc((size_t)elems * 2);
        wl[i] = (short*)alloc((size_t)elems * 2);
        wa.w[i] = wsrc[i]; wa.hi[i] = wh[i]; wa.lo[i] = wl[i];
        wa.K[i] = wdims[i][0]; wa.Nc[i] = wdims[i][1]; wa.base[i] = base;
        base += elems;
    }
    wa.total = base;
    wa.cursor = cursor;
    wa.n = N;
    wa.xf = x;
    wa.xh = XH;
    wa.nx4 = N * 16;
    (void)ws_size; (void)n_in; (void)out_size;

    const float inv_n = 1.0f / (float)N;

    // ---- weight split + cursor zero + x->fp16 ----
    int wgrid = wa.nx4;
    if (N > wgrid) wgrid = N;
    if (wa.total > wgrid) wgrid = wa.total;
    wsplit_all<<<(wgrid + 255) / 256, 256, 0, stream>>>(wa);

    // ---- CSR build ----
    hist_kernel<<<(E + 255) / 256, 256, 0, stream>>>(dst, cursor, E);
    int chunks = (N + 1023) / 1024;
    scan_part_kernel<<<chunks, 1024, 0, stream>>>(cursor, starts, bsum, N);
    scan_tops_kernel<<<1, 128, 0, stream>>>(bsum, chunks);
    scan_add_kernel<<<chunks, 1024, 0, stream>>>(starts, cursor, bsum, N, E);
    int P = N / 8;
    if (P < 1) P = 1;
    fill_part_kernel<<<1024, 256, 0, stream>>>(src, dst, cursor, srcs, E, P);

    const int nb = (N + 127) / 128;

    // ---- layer 0 ----
    gather_hh<64, false, true><<<N, 64, 0, stream>>>(
        XH, starts, srcs, nullptr, PRE0, sums, 256, N);
    gemm16<64, 128, false, true, true, true><<<nb * 2, 256, 0, stream>>>(
        PRE0, wh[0], wl[0], b1[0], nullptr, nullptr, nullptr, inv_n,
        nullptr, HA, sums, N);
    gemm16<128, 128, true, false, true, true><<<nb * 2, 256, 0, stream>>>(
        HA, wh[1], wl[1], b2[0], sums, gg[0], be[0], inv_n,
        nullptr, HB, nullptr, N);

    // ---- layer 1 ----
    gather_hh<128, false, true><<<N, 64, 0, stream>>>(
        HB, starts, srcs, nullptr, HA, sums, 256, N);
    gemm16<128, 128, false, true, true, true><<<nb * 2, 256, 0, stream>>>(
        HA, wh[2], wl[2], b1[1], nullptr, nullptr, nullptr, inv_n,
        nullptr, HB, sums, N);
    gemm16<128, 128, true, false, true, true><<<nb * 2, 256, 0, stream>>>(
        HB, wh[3], wl[3], b2[1], sums, gg[1], be[1], inv_n,
        nullptr, HA, nullptr, N);

    // ---- layer 2 (aggregation commuted through W1) ----
    gemm16<128, 64, false, false, false, true><<<nb, 256, 0, stream>>>(
        HA, wh[4], wl[4], nullptr, nullptr, nullptr, nullptr, inv_n,
        nullptr, XH, nullptr, N);
    gather_hh<64, true, true><<<N, 64, 0, stream>>>(
        XH, starts, srcs, b1[2], PRE0, sums, 128, N);
    stats_h<64><<<512, 256, 0, stream>>>(PRE0, sums, N);
    gemm16<64, 64, true, false, true, false><<<nb, 256, 0, stream>>>(
        PRE0, wh[5], wl[5], b2[2], sums, gg[2], be[2], inv_n,
        (float*)d_out, nullptr, nullptr, N);
}